// Round 6
// baseline (598.260 us; speedup 1.0000x reference)
//
#include <hip/hip_runtime.h>
#include <hip/hip_bf16.h>
#include <stdint.h>

// GSC_kan: two grouped KAN convs (1x1, 3x3; G=8) + BatchNorm.
// Round 6: R5's hoisting path never ran (ws_size < 323 MB -> fallback).
// Fix: batch-chunked hoisting, 4 batches per chunk (~82 MB, L3-resident).
// kan1f: conv1 + feature epilogue (packed bf16, zero-padded 66x66 planes).
// kan2_ldg: pure global->LDS copy + MFMA, loads prefetched across MFMA.

#define NB 8
#define NF 9
#define CIN 128
#define COUT 256
#define GROUPS 8
#define HW 4096
#define BATCH 16

#define WFS_ELEMS 589824   // 256 * 32 * 8 * 9
#define WFB_ELEMS 73728    // 256 * 32 * 9

#define PY 66
#define PCELLS (66 * 66)   // 4356
#define CB 4               // batches per chunk

typedef __attribute__((ext_vector_type(8))) short bf16x8;
typedef __attribute__((ext_vector_type(4))) float f32x4;

__device__ __forceinline__ unsigned bf16r(float f) {
    union { float f; unsigned u; } c; c.f = f;
    unsigned r = c.u + 0x7FFF + ((c.u >> 16) & 1);   // RNE
    return r >> 16;
}
__device__ __forceinline__ unsigned bfpack(float lo, float hi) {
    return bf16r(lo) | (bf16r(hi) << 16);
}

// uniform-knot cubic B-spline: 4 nonzero cardinal weights at interval k.
__device__ __forceinline__ void spline_w(float v, float& w0, float& w1,
                                         float& w2, float& w3, int& k) {
    float s = (v + 2.2f) * 2.5f;
    float fk = floorf(s);
    k = (int)fk;
    float u = s - fk;
    float um = 1.0f - u;
    float u2 = u * u, u3 = u2 * u;
    w0 = um * um * um * (1.0f / 6.0f);
    w1 = (3.0f * u3 - 6.0f * u2 + 4.0f) * (1.0f / 6.0f);
    w2 = (-3.0f * u3 + 3.0f * u2 + 3.0f * u + 1.0f) * (1.0f / 6.0f);
    w3 = u3 * (1.0f / 6.0f);
}

__device__ __forceinline__ void spline_bases(float v, float* __restrict__ bs) {
    float w0, w1, w2, w3; int k;
    spline_w(v, w0, w1, w2, w3, k);
#pragma unroll
    for (int idx = 0; idx < 8; ++idx) {
        int d = idx - k + 3;
        float r = (d == 0) ? w0 : 0.0f;
        r = (d == 1) ? w1 : r;
        r = (d == 2) ? w2 : r;
        r = (d == 3) ? w3 : r;
        bs[idx] = r;
    }
}

__device__ __forceinline__ void kan_features_fast(float v, float* __restrict__ f) {
    f[0] = v / (1.0f + __expf(-v));
    spline_bases(v, f + 1);
}

// ---- repack: wp1 fp32 [g][c16][f9][co32]; wfs/wfb bf16 B-fragment layouts ----
__global__ void __launch_bounds__(256) repack2_kernel(
    const float* __restrict__ wb1, const float* __restrict__ ws1,
    const float* __restrict__ wb2, const float* __restrict__ ws2,
    float* __restrict__ wp1, unsigned short* __restrict__ wfs,
    unsigned short* __restrict__ wfb) {
    int i = blockIdx.x * 256 + threadIdx.x;
    if (i < 8 * 16 * 9 * 32) {
        int co = i & 31;
        int t = i >> 5;
        int f = t % 9; t /= 9;
        int c = t & 15; int g = t >> 4;
        int cog = g * 32 + co;
        wp1[i] = (f == 0) ? wb1[cog * 16 + c]
                          : ws1[cog * 128 + c * 8 + (f - 1)];
    }
    if (i < WFB_ELEMS) {
        int j = i & 7;
        int lane = (i >> 3) & 63;
        int nf = (i >> 9) & 1;
        int t = i >> 10;
        int dy = t % 3; t /= 3;
        int dx = t % 3; t /= 3;
        int g = t;
        int ch = (lane >> 4) * 8 + j;
        int cog = g * 32 + nf * 16 + (lane & 15);
        wfb[i] = (unsigned short)bf16r(wb2[((cog * 32 + ch) * 3 + dy) * 3 + dx]);
    }
    if (i < WFS_ELEMS) {
        int j = i & 7;
        int t = i >> 3;
        int lane = t & 63; t >>= 6;
        int nf = t & 1; t >>= 1;
        int dy = t % 3; t /= 3;
        int dx = t % 3; t /= 3;
        int cc = t & 7; t >>= 3;
        int g = t;
        int c_loc = cc * 4 + (lane >> 4);
        int cog = g * 32 + nf * 16 + (lane & 15);
        float v = ws2[((cog * 256 + c_loc * 8 + j) * 3 + dy) * 3 + dx];
        wfs[i] = (unsigned short)bf16r(v);
    }
}

// ---- zero padded borders: sfe = CB*256 planes (16B cells), bfe = CB*8 (64B) ----
__global__ void __launch_bounds__(256) border_kernel(
    uint4* __restrict__ sfe, uint4* __restrict__ bfe) {
    int i = blockIdx.x * 256 + threadIdx.x;
    if (i >= CB * 256 * 260) return;
    int plane = i / 260;
    int r = i - plane * 260;
    int yp, xp;
    if (r < 66)       { yp = 0;  xp = r; }
    else if (r < 132) { yp = 65; xp = r - 66; }
    else { int q = r - 132; yp = 1 + (q >> 1); xp = (q & 1) ? 65 : 0; }
    uint4 z = {0, 0, 0, 0};
    sfe[(size_t)plane * PCELLS + yp * PY + xp] = z;
    if (i < CB * 8 * 260) {
        size_t c = ((size_t)plane * PCELLS + yp * PY + xp) * 4;
        bfe[c] = z; bfe[c + 1] = z; bfe[c + 2] = z; bfe[c + 3] = z;
    }
}

// ---- layer 1 fused: 1x1 grouped KAN conv + feature epilogue (per chunk) ----
__global__ void __launch_bounds__(256) kan1f_kernel(
    const float* __restrict__ x, const float* __restrict__ wp1,
    const float* __restrict__ bb1, uint4* __restrict__ sfe,
    uint4* __restrict__ bfe, int b0) {
    int tid = threadIdx.x;
    int blk = blockIdx.x;                // (b_local*8 + g)*16 + t
    int t = blk & 15;
    int g = (blk >> 4) & 7;
    int bl = blk >> 7;                   // 0..CB-1
    int b = b0 + bl;
    int pos = t * 256 + tid;
    int y = pos >> 6, xx = pos & 63;

    float acc[32];
    const float* bb = bb1 + g * 32;
#pragma unroll
    for (int co = 0; co < 32; ++co) acc[co] = bb[co];

    for (int c = 0; c < 16; ++c) {
        float v = x[(b * CIN + g * 16 + c) * HW + pos];
        float ft[NF];
        kan_features_fast(v, ft);
        const float* wp = wp1 + ((g * 16 + c) * 9) * 32;
        for (int f = 0; f < NF; ++f) {
            float fv = ft[f];
#pragma unroll
            for (int co = 0; co < 32; ++co)
                acc[co] = fmaf(wp[f * 32 + co], fv, acc[co]);
        }
    }
    // feature epilogue
    size_t cell = (size_t)(y + 1) * PY + (xx + 1);
    size_t sbase = ((size_t)(bl * 256 + g * 32)) * PCELLS + cell;
    unsigned su[16];
#pragma unroll
    for (int co = 0; co < 32; ++co) {
        float v = acc[co];
        float sv = v / (1.0f + __expf(-v));
        float bs[8];
        spline_bases(v, bs);
        uint4 pk;
        pk.x = bfpack(bs[0], bs[1]);
        pk.y = bfpack(bs[2], bs[3]);
        pk.z = bfpack(bs[4], bs[5]);
        pk.w = bfpack(bs[6], bs[7]);
        sfe[sbase + (size_t)co * PCELLS] = pk;
        unsigned h = bf16r(sv);
        if (co & 1) su[co >> 1] |= h << 16;
        else        su[co >> 1] = h;
    }
    size_t bbase = (((size_t)(bl * 8 + g)) * PCELLS + cell) * 4;
#pragma unroll
    for (int q = 0; q < 4; ++q) {
        uint4 o = {su[q * 4], su[q * 4 + 1], su[q * 4 + 2], su[q * 4 + 3]};
        bfe[bbase + q] = o;
    }
}

// ---- layer 2: pure copy + MFMA. LDS [ch][324][16B], per chunk. ----
__global__ void __launch_bounds__(256) kan2_ldg_kernel(
    const uint4* __restrict__ sfe, const uint4* __restrict__ bfe,
    const bf16x8* __restrict__ wfs, const bf16x8* __restrict__ wfb,
    const float* __restrict__ bb2, float* __restrict__ h2, int b0) {
    __shared__ __align__(16) unsigned char lds[41472];
    unsigned char* spl = lds;            // 20736 B: (ch*324 + p) * 16
    unsigned char* slu = lds + 20736;    // 20736 B: (cq*324 + p) * 16

    const int tid = threadIdx.x;
    const int lane = tid & 63;
    const int w = tid >> 6;
    const int blk = blockIdx.x;
    const int tile = blk & 15;
    const int g = (blk >> 4) & 7;
    const int bl = blk >> 7;             // 0..CB-1
    const int b = b0 + bl;
    const int ty = (tile >> 2) * 16, tx = (tile & 3) * 16;
    const int lrow = lane & 15;
    const int lhi = lane >> 4;

    f32x4 acc[4][2];
#pragma unroll
    for (int y = 0; y < 4; ++y)
#pragma unroll
        for (int nf = 0; nf < 2; ++nf) {
            float bias = bb2[g * 32 + nf * 16 + lrow];
            acc[y][nf] = (f32x4){bias, bias, bias, bias};
        }

    const int hybase = w * 4;
    const size_t sfe_base = ((size_t)(bl * 256 + g * 32)) * PCELLS;
    const size_t bfe_base = ((size_t)(bl * 8 + g)) * PCELLS * 4;

    uint4 st[6];

    // ---- stage silu plane (once): e = p*4 + cq, coalesced 64B cells ----
#pragma unroll
    for (int it = 0; it < 6; ++it) {
        int e = tid + it * 256;
        if (e < 1296) {
            int p = e >> 2, cq = e & 3;
            int hy = p / 18, hx = p - hy * 18;
            st[it] = bfe[bfe_base + ((size_t)(ty + hy) * PY + (tx + hx)) * 4 + cq];
        }
    }
#pragma unroll
    for (int it = 0; it < 6; ++it) {
        int e = tid + it * 256;
        if (e < 1296) {
            int p = e >> 2, cq = e & 3;
            *reinterpret_cast<uint4*>(slu + (cq * 324 + p) * 16) = st[it];
        }
    }
    // ---- stage spline chunk 0 ----
#pragma unroll
    for (int it = 0; it < 6; ++it) {
        int e = tid + it * 256;
        if (e < 1296) {
            int ch = e / 324, p = e - ch * 324;
            int hy = p / 18, hx = p - hy * 18;
            st[it] = sfe[sfe_base + (size_t)ch * PCELLS +
                         (size_t)(ty + hy) * PY + (tx + hx)];
        }
    }
#pragma unroll
    for (int it = 0; it < 6; ++it) {
        int e = tid + it * 256;
        if (e < 1296)
            *reinterpret_cast<uint4*>(spl + e * 16) = st[it];
    }
    // ---- issue loads for chunk 1 (held in regs across MFMA of chunk 0) ----
#pragma unroll
    for (int it = 0; it < 6; ++it) {
        int e = tid + it * 256;
        if (e < 1296) {
            int ch = e / 324, p = e - ch * 324;
            int hy = p / 18, hx = p - hy * 18;
            st[it] = sfe[sfe_base + (size_t)(4 + ch) * PCELLS +
                         (size_t)(ty + hy) * PY + (tx + hx)];
        }
    }
    __syncthreads();

    for (int cc = 0; cc < 8; ++cc) {
        // MFMA phase on current chunk
#pragma unroll
        for (int dx = 0; dx < 3; ++dx) {
            bf16x8 bf[3][2];
            const bf16x8* wp = wfs + (size_t)((((g * 8 + cc) * 3 + dx) * 3) * 2) * 64;
#pragma unroll
            for (int dy = 0; dy < 3; ++dy)
#pragma unroll
                for (int nf = 0; nf < 2; ++nf)
                    bf[dy][nf] = wp[(dy * 2 + nf) * 64 + lane];
#pragma unroll
            for (int hr = 0; hr < 6; ++hr) {
                int p = (hybase + hr) * 18 + lrow + dx;
                bf16x8 af = *reinterpret_cast<const bf16x8*>(spl + (lhi * 324 + p) * 16);
#pragma unroll
                for (int dy = 0; dy < 3; ++dy) {
                    int y = hr - dy;
                    if (y >= 0 && y < 4) {
                        acc[y][0] = __builtin_amdgcn_mfma_f32_16x16x32_bf16(af, bf[dy][0], acc[y][0], 0, 0, 0);
                        acc[y][1] = __builtin_amdgcn_mfma_f32_16x16x32_bf16(af, bf[dy][1], acc[y][1], 0, 0, 0);
                    }
                }
            }
        }
        __syncthreads();   // all waves done reading this chunk
        if (cc < 7) {
            // write next chunk (regs already loaded), issue loads for cc+2
#pragma unroll
            for (int it = 0; it < 6; ++it) {
                int e = tid + it * 256;
                if (e < 1296)
                    *reinterpret_cast<uint4*>(spl + e * 16) = st[it];
            }
            if (cc < 6) {
#pragma unroll
                for (int it = 0; it < 6; ++it) {
                    int e = tid + it * 256;
                    if (e < 1296) {
                        int ch = e / 324, p = e - ch * 324;
                        int hy = p / 18, hx = p - hy * 18;
                        st[it] = sfe[sfe_base + (size_t)((cc + 2) * 4 + ch) * PCELLS +
                                     (size_t)(ty + hy) * PY + (tx + hx)];
                    }
                }
            }
            __syncthreads();
        }
    }
    // base branch from slu (staged at start)
#pragma unroll
    for (int dx = 0; dx < 3; ++dx) {
        bf16x8 bf[3][2];
        const bf16x8* wp = wfb + (size_t)(((g * 3 + dx) * 3) * 2) * 64;
#pragma unroll
        for (int dy = 0; dy < 3; ++dy)
#pragma unroll
            for (int nf = 0; nf < 2; ++nf)
                bf[dy][nf] = wp[(dy * 2 + nf) * 64 + lane];
#pragma unroll
        for (int hr = 0; hr < 6; ++hr) {
            int p = (hybase + hr) * 18 + lrow + dx;
            bf16x8 af = *reinterpret_cast<const bf16x8*>(slu + (lhi * 324 + p) * 16);
#pragma unroll
            for (int dy = 0; dy < 3; ++dy) {
                int y = hr - dy;
                if (y >= 0 && y < 4) {
                    acc[y][0] = __builtin_amdgcn_mfma_f32_16x16x32_bf16(af, bf[dy][0], acc[y][0], 0, 0, 0);
                    acc[y][1] = __builtin_amdgcn_mfma_f32_16x16x32_bf16(af, bf[dy][1], acc[y][1], 0, 0, 0);
                }
            }
        }
    }
#pragma unroll
    for (int y = 0; y < 4; ++y) {
        int oy = ty + w * 4 + y;
#pragma unroll
        for (int nf = 0; nf < 2; ++nf) {
            int co = g * 32 + nf * 16 + lrow;
            float4 o = {acc[y][nf][0], acc[y][nf][1], acc[y][nf][2], acc[y][nf][3]};
            *reinterpret_cast<float4*>(
                &h2[(((size_t)b * COUT + co) * 64 + oy) * 64 + tx + lhi * 4]) = o;
        }
    }
}

// ==================== fallback (proven R4) kernels ====================
__global__ void __launch_bounds__(256) kan1_kernel(
    const float* __restrict__ x, const float* __restrict__ wp1,
    const float* __restrict__ bb1, float* __restrict__ h1) {
    int tid = threadIdx.x;
    int blk = blockIdx.x;
    int t = blk & 15;
    int g = (blk >> 4) & 7;
    int b = blk >> 7;
    int pos = t * 256 + tid;

    float acc[32];
    const float* bb = bb1 + g * 32;
#pragma unroll
    for (int co = 0; co < 32; ++co) acc[co] = bb[co];

    for (int c = 0; c < 16; ++c) {
        float v = x[(b * CIN + g * 16 + c) * HW + pos];
        float ft[NF];
        kan_features_fast(v, ft);
        const float* wp = wp1 + ((g * 16 + c) * 9) * 32;
        for (int f = 0; f < NF; ++f) {
            float fv = ft[f];
#pragma unroll
            for (int co = 0; co < 32; ++co)
                acc[co] = fmaf(wp[f * 32 + co], fv, acc[co]);
        }
    }
    float* op = h1 + (b * COUT + g * 32) * HW + pos;
#pragma unroll
    for (int co = 0; co < 32; ++co) op[co * HW] = acc[co];
}

__global__ void __launch_bounds__(256) kan2_mfma_kernel(
    const float* __restrict__ h1, const bf16x8* __restrict__ wfs,
    const bf16x8* __restrict__ wfb, const float* __restrict__ bb2,
    float* __restrict__ h2) {
    __shared__ __align__(16) unsigned char lds[41472];
    unsigned char* spl = lds;
    unsigned char* slu = lds + 20736;

    const int tid = threadIdx.x;
    const int lane = tid & 63;
    const int w = tid >> 6;
    const int blk = blockIdx.x;
    const int tile = blk & 15;
    const int g = (blk >> 4) & 7;
    const int b = blk >> 7;
    const int ty = (tile >> 2) * 16, tx = (tile & 3) * 16;
    const int lrow = lane & 15;
    const int lhi = lane >> 4;

    f32x4 acc[4][2];
#pragma unroll
    for (int y = 0; y < 4; ++y)
#pragma unroll
        for (int nf = 0; nf < 2; ++nf) {
            float bias = bb2[g * 32 + nf * 16 + lrow];
            acc[y][nf] = (f32x4){bias, bias, bias, bias};
        }

    const float* h1g = h1 + (size_t)(b * COUT + g * 32) * HW;
    const int hybase = w * 4;

    for (int cc = 0; cc < 8; ++cc) {
        __syncthreads();
        for (int e = tid; e < 1296; e += 256) {
            int ch = e / 324;
            int p = e - ch * 324;
            int hy = p / 18, hx = p - hy * 18;
            int iy = ty + hy - 1, ix = tx + hx - 1;
            bool in = ((unsigned)iy < 64u) & ((unsigned)ix < 64u);
            float v = in ? h1g[(cc * 4 + ch) * HW + iy * 64 + ix] : 0.0f;
            float sv = v / (1.0f + __expf(-v));
            float w0, w1, w2, w3; int k;
            spline_w(v, w0, w1, w2, w3, k);
            if (!in) k = -1000;
            float bs[8];
#pragma unroll
            for (int idx = 0; idx < 8; ++idx) {
                int d = idx - k + 3;
                float r = (d == 0) ? w0 : 0.0f;
                r = (d == 1) ? w1 : r;
                r = (d == 2) ? w2 : r;
                r = (d == 3) ? w3 : r;
                bs[idx] = r;
            }
            int key = (p >> 1) & 3;
            uint4 pk;
            pk.x = bfpack(bs[0], bs[1]);
            pk.y = bfpack(bs[2], bs[3]);
            pk.z = bfpack(bs[4], bs[5]);
            pk.w = bfpack(bs[6], bs[7]);
            *reinterpret_cast<uint4*>(spl + p * 64 + ((ch ^ key) << 4)) = pk;
            int cg = cc * 4 + ch;
            *reinterpret_cast<unsigned short*>(
                slu + p * 64 + (((cg >> 3) ^ key) << 4) + ((cg * 2) & 15)) =
                (unsigned short)bf16r(sv);
        }
        __syncthreads();
#pragma unroll
        for (int dx = 0; dx < 3; ++dx) {
            bf16x8 bf[3][2];
            const bf16x8* wp = wfs + (size_t)((((g * 8 + cc) * 3 + dx) * 3) * 2) * 64;
#pragma unroll
            for (int dy = 0; dy < 3; ++dy)
#pragma unroll
                for (int nf = 0; nf < 2; ++nf)
                    bf[dy][nf] = wp[(dy * 2 + nf) * 64 + lane];
#pragma unroll
            for (int hr = 0; hr < 6; ++hr) {
                int p = (hybase + hr) * 18 + lrow + dx;
                int ra = p * 64 + (((lhi ^ ((p >> 1) & 3))) << 4);
                bf16x8 af = *reinterpret_cast<const bf16x8*>(spl + ra);
#pragma unroll
                for (int dy = 0; dy < 3; ++dy) {
                    int y = hr - dy;
                    if (y >= 0 && y < 4) {
                        acc[y][0] = __builtin_amdgcn_mfma_f32_16x16x32_bf16(af, bf[dy][0], acc[y][0], 0, 0, 0);
                        acc[y][1] = __builtin_amdgcn_mfma_f32_16x16x32_bf16(af, bf[dy][1], acc[y][1], 0, 0, 0);
                    }
                }
            }
        }
    }
#pragma unroll
    for (int dx = 0; dx < 3; ++dx) {
        bf16x8 bf[3][2];
        const bf16x8* wp = wfb + (size_t)(((g * 3 + dx) * 3) * 2) * 64;
#pragma unroll
        for (int dy = 0; dy < 3; ++dy)
#pragma unroll
            for (int nf = 0; nf < 2; ++nf)
                bf[dy][nf] = wp[(dy * 2 + nf) * 64 + lane];
#pragma unroll
        for (int hr = 0; hr < 6; ++hr) {
            int p = (hybase + hr) * 18 + lrow + dx;
            int ra = p * 64 + (((lhi ^ ((p >> 1) & 3))) << 4);
            bf16x8 af = *reinterpret_cast<const bf16x8*>(slu + ra);
#pragma unroll
            for (int dy = 0; dy < 3; ++dy) {
                int y = hr - dy;
                if (y >= 0 && y < 4) {
                    acc[y][0] = __builtin_amdgcn_mfma_f32_16x16x32_bf16(af, bf[dy][0], acc[y][0], 0, 0, 0);
                    acc[y][1] = __builtin_amdgcn_mfma_f32_16x16x32_bf16(af, bf[dy][1], acc[y][1], 0, 0, 0);
                }
            }
        }
    }
#pragma unroll
    for (int y = 0; y < 4; ++y) {
        int oy = ty + w * 4 + y;
#pragma unroll
        for (int nf = 0; nf < 2; ++nf) {
            int co = g * 32 + nf * 16 + lrow;
            float4 o = {acc[y][nf][0], acc[y][nf][1], acc[y][nf][2], acc[y][nf][3]};
            *reinterpret_cast<float4*>(
                &h2[(((size_t)b * COUT + co) * 64 + oy) * 64 + tx + lhi * 4]) = o;
        }
    }
}

// ---- BN stage 1: per-(b,co) plane partial sums ----
__global__ void __launch_bounds__(256) bnp1_kernel(
    const float* __restrict__ h2, float* __restrict__ partial) {
    int bc = blockIdx.x;
    int tid = threadIdx.x;
    const float4* p = reinterpret_cast<const float4*>(h2 + (size_t)bc * HW);
    float s = 0.0f, ss = 0.0f;
#pragma unroll
    for (int it = 0; it < 4; ++it) {
        float4 v = p[tid + it * 256];
        s += v.x + v.y + v.z + v.w;
        ss = fmaf(v.x, v.x, ss); ss = fmaf(v.y, v.y, ss);
        ss = fmaf(v.z, v.z, ss); ss = fmaf(v.w, v.w, ss);
    }
    __shared__ float r1[256], r2[256];
    r1[tid] = s; r2[tid] = ss;
    __syncthreads();
    for (int o = 128; o > 0; o >>= 1) {
        if (tid < o) { r1[tid] += r1[tid + o]; r2[tid] += r2[tid + o]; }
        __syncthreads();
    }
    if (tid == 0) { partial[2 * bc] = r1[0]; partial[2 * bc + 1] = r2[0]; }
}

// ---- BN stage 2: reduce over batch, write scale/shift ----
__global__ void __launch_bounds__(256) bnp2_kernel(
    const float* __restrict__ partial, const float* __restrict__ gamma,
    const float* __restrict__ beta, float* __restrict__ stats) {
    int co = threadIdx.x;
    float s = 0.0f, ss = 0.0f;
    for (int b = 0; b < BATCH; ++b) {
        s += partial[2 * (b * 256 + co)];
        ss += partial[2 * (b * 256 + co) + 1];
    }
    const float invn = 1.0f / 65536.0f;
    float mean = s * invn;
    float var = ss * invn - mean * mean;
    float sc = gamma[co] * rsqrtf(var + 1e-5f);
    stats[2 * co] = sc;
    stats[2 * co + 1] = beta[co] - mean * sc;
}

// ---- BN apply (in place on d_out) ----
__global__ void __launch_bounds__(256) bnapply_kernel(
    float* __restrict__ h2, const float* __restrict__ stats, int n4) {
    int i = blockIdx.x * 256 + threadIdx.x;
    if (i >= n4) return;
    int co = (i >> 10) & 255;
    float sc = stats[2 * co], sh = stats[2 * co + 1];
    float4 v = reinterpret_cast<float4*>(h2)[i];
    float4 o;
    o.x = fmaf(v.x, sc, sh);
    o.y = fmaf(v.y, sc, sh);
    o.z = fmaf(v.z, sc, sh);
    o.w = fmaf(v.w, sc, sh);
    reinterpret_cast<float4*>(h2)[i] = o;
}

extern "C" void kernel_launch(void* const* d_in, const int* in_sizes, int n_in,
                              void* d_out, int out_size, void* d_ws, size_t ws_size,
                              hipStream_t stream) {
    const float* x   = (const float*)d_in[0];
    const float* wb1 = (const float*)d_in[1];
    const float* bb1 = (const float*)d_in[2];
    const float* ws1 = (const float*)d_in[3];
    const float* wb2 = (const float*)d_in[4];
    const float* bb2 = (const float*)d_in[5];
    const float* ws2 = (const float*)d_in[6];
    const float* gamma = (const float*)d_in[7];
    const float* beta  = (const float*)d_in[8];

    char* ws = (char*)d_ws;
    float* wp1   = (float*)ws;                                    // 147,456 B
    unsigned short* wfs = (unsigned short*)(ws + 147456);         // 1,179,648 B
    unsigned short* wfb = (unsigned short*)(ws + 1327104);        // 147,456 B
    float* partial = (float*)(ws + 1474560);                      // 32,768 B
    float* stats   = (float*)(ws + 1507328);                      // 2,048 B
    const size_t BASE = 1509376;

    float* h2 = (float*)d_out;   // conv2 output in d_out; BN in-place

    const size_t SFE_BYTES = (size_t)CB * COUT * PCELLS * 16;   // 71,368,704
    const size_t BFE_BYTES = (size_t)CB * GROUPS * PCELLS * 64; //  8,921,088
    const size_t NEED_A = BASE + SFE_BYTES + BFE_BYTES;         // ~81.8 MB

    repack2_kernel<<<(WFS_ELEMS + 255) / 256, 256, 0, stream>>>(
        wb1, ws1, wb2, ws2, wp1, wfs, wfb);

    if (ws_size >= NEED_A) {
        uint4* sfe = (uint4*)(ws + BASE);
        uint4* bfe = (uint4*)(ws + BASE + SFE_BYTES);
        border_kernel<<<(CB * 256 * 260 + 255) / 256, 256, 0, stream>>>(sfe, bfe);
        for (int b0 = 0; b0 < BATCH; b0 += CB) {
            kan1f_kernel<<<CB * GROUPS * 16, 256, 0, stream>>>(
                x, wp1, bb1, sfe, bfe, b0);
            kan2_ldg_kernel<<<CB * GROUPS * 16, 256, 0, stream>>>(
                sfe, bfe, (const bf16x8*)wfs, (const bf16x8*)wfb, bb2, h2, b0);
        }
    } else {
        float* h1 = (float*)(ws + BASE);
        kan1_kernel<<<BATCH * GROUPS * 16, 256, 0, stream>>>(x, wp1, bb1, h1);
        kan2_mfma_kernel<<<BATCH * GROUPS * 16, 256, 0, stream>>>(
            h1, (const bf16x8*)wfs, (const bf16x8*)wfb, bb2, h2);
    }

    bnp1_kernel<<<BATCH * COUT, 256, 0, stream>>>(h2, partial);
    bnp2_kernel<<<1, 256, 0, stream>>>(partial, gamma, beta, stats);
    bnapply_kernel<<<(4194304 + 255) / 256, 256, 0, stream>>>(
        h2, stats, 4194304);
}

// Round 7
// 272.918 us; speedup vs baseline: 2.1921x; 2.1921x over previous
//
#include <hip/hip_runtime.h>
#include <hip/hip_bf16.h>
#include <stdint.h>

// GSC_kan: two grouped KAN convs (1x1, 3x3; G=8) + BatchNorm.
// Round 7: revert R6's feature-materialization (HBM round-trip + tiny grids
// made it 2x slower). Back to R5 structure; attack kan2's measured VALU
// bottleneck: staging row built via v_cvt_pk_bf16_f32 + 16-bit-granule
// variable placement (~30 ops vs ~110), divides hoisted out of the loop.
// BN stats fused into kan2's epilogue (drops bnp1's 67MB re-read).

#define NB 8
#define NF 9
#define CIN 128
#define COUT 256
#define GROUPS 8
#define HW 4096
#define BATCH 16

#define WFS_ELEMS 589824   // 256 * 32 * 8 * 9
#define WFB_ELEMS 73728    // 256 * 32 * 9

typedef __attribute__((ext_vector_type(8))) short bf16x8;
typedef __attribute__((ext_vector_type(4))) float f32x4;

__device__ __forceinline__ unsigned bf16r(float f) {
    union { float f; unsigned u; } c; c.f = f;
    unsigned r = c.u + 0x7FFF + ((c.u >> 16) & 1);   // RNE
    return r >> 16;
}

// uniform-knot cubic B-spline: 4 nonzero cardinal weights at interval k.
// knots t_j = -1 + (j-3)*0.4 (j=0..11); s=(v+2.2)*2.5; nonzero bases k-3..k.
__device__ __forceinline__ void spline_w(float v, float& w0, float& w1,
                                         float& w2, float& w3, int& k) {
    float s = (v + 2.2f) * 2.5f;
    float fk = floorf(s);
    k = (int)fk;
    float u = s - fk;
    float um = 1.0f - u;
    float u2 = u * u, u3 = u2 * u;
    w0 = um * um * um * (1.0f / 6.0f);
    w1 = (3.0f * u3 - 6.0f * u2 + 4.0f) * (1.0f / 6.0f);
    w2 = (-3.0f * u3 + 3.0f * u2 + 3.0f * u + 1.0f) * (1.0f / 6.0f);
    w3 = u3 * (1.0f / 6.0f);
}

__device__ __forceinline__ void kan_features_fast(float v, float* __restrict__ f) {
    f[0] = v / (1.0f + __expf(-v));
    float w0, w1, w2, w3; int k;
    spline_w(v, w0, w1, w2, w3, k);
#pragma unroll
    for (int idx = 0; idx < 8; ++idx) {
        int d = idx - k + 3;
        float r = (d == 0) ? w0 : 0.0f;
        r = (d == 1) ? w1 : r;
        r = (d == 2) ? w2 : r;
        r = (d == 3) ? w3 : r;
        f[1 + idx] = r;
    }
}

// ---- repack: wp1 fp32 [g][c16][f9][co32]; wfs/wfb bf16 B-fragment layouts ----
__global__ void __launch_bounds__(256) repack2_kernel(
    const float* __restrict__ wb1, const float* __restrict__ ws1,
    const float* __restrict__ wb2, const float* __restrict__ ws2,
    float* __restrict__ wp1, unsigned short* __restrict__ wfs,
    unsigned short* __restrict__ wfb) {
    int i = blockIdx.x * 256 + threadIdx.x;
    if (i < 8 * 16 * 9 * 32) {
        int co = i & 31;
        int t = i >> 5;
        int f = t % 9; t /= 9;
        int c = t & 15; int g = t >> 4;
        int cog = g * 32 + co;
        wp1[i] = (f == 0) ? wb1[cog * 16 + c]
                          : ws1[cog * 128 + c * 8 + (f - 1)];
    }
    if (i < WFB_ELEMS) {
        int j = i & 7;
        int lane = (i >> 3) & 63;
        int nf = (i >> 9) & 1;
        int t = i >> 10;
        int dy = t % 3; t /= 3;
        int dx = t % 3; t /= 3;
        int g = t;
        int ch = (lane >> 4) * 8 + j;
        int cog = g * 32 + nf * 16 + (lane & 15);
        wfb[i] = (unsigned short)bf16r(wb2[((cog * 32 + ch) * 3 + dy) * 3 + dx]);
    }
    if (i < WFS_ELEMS) {
        int j = i & 7;
        int t = i >> 3;
        int lane = t & 63; t >>= 6;
        int nf = t & 1; t >>= 1;
        int dy = t % 3; t /= 3;
        int dx = t % 3; t /= 3;
        int cc = t & 7; t >>= 3;
        int g = t;
        int c_loc = cc * 4 + (lane >> 4);
        int cog = g * 32 + nf * 16 + (lane & 15);
        float v = ws2[((cog * 256 + c_loc * 8 + j) * 3 + dy) * 3 + dx];
        wfs[i] = (unsigned short)bf16r(v);
    }
}

// ---- layer 1: 1x1 grouped KAN conv (fp32 VALU) ----
__global__ void __launch_bounds__(256) kan1_kernel(
    const float* __restrict__ x, const float* __restrict__ wp1,
    const float* __restrict__ bb1, float* __restrict__ h1) {
    int tid = threadIdx.x;
    int blk = blockIdx.x;
    int t = blk & 15;
    int g = (blk >> 4) & 7;
    int b = blk >> 7;
    int pos = t * 256 + tid;

    float acc[32];
    const float* bb = bb1 + g * 32;
#pragma unroll
    for (int co = 0; co < 32; ++co) acc[co] = bb[co];

    for (int c = 0; c < 16; ++c) {
        float v = x[(b * CIN + g * 16 + c) * HW + pos];
        float ft[NF];
        kan_features_fast(v, ft);
        const float* wp = wp1 + ((g * 16 + c) * 9) * 32;
        for (int f = 0; f < NF; ++f) {
            float fv = ft[f];
#pragma unroll
            for (int co = 0; co < 32; ++co)
                acc[co] = fmaf(wp[f * 32 + co], fv, acc[co]);
        }
    }
    float* op = h1 + (b * COUT + g * 32) * HW + pos;
#pragma unroll
    for (int co = 0; co < 32; ++co) op[co * HW] = acc[co];
}

// ---- stage one halo element: packed-row construction (~30 VALU ops) ----
// row (8 bf16) = zeros except w0..w3 at idx kk..kk+3 (kk=k-3), built from
// two cvt_pk words placed at 16-bit granularity via even/odd alignment.
__device__ __forceinline__ void stage_one(
    const float* __restrict__ h1c, unsigned char* __restrict__ spl,
    unsigned char* __restrict__ slu, int p, int hy, int hx,
    int ty, int tx, int ch, int cg) {
    int iy = ty + hy - 1, ix = tx + hx - 1;
    bool in = ((unsigned)iy < 64u) & ((unsigned)ix < 64u);
    float v = in ? h1c[iy * 64 + ix] : 0.0f;
    float sv = v / (1.0f + __expf(-v));          // silu(0)=0 handles pad
    float w0, w1, w2, w3; int k;
    spline_w(v, w0, w1, w2, w3, k);
    unsigned W0, W1;
    asm("v_cvt_pk_bf16_f32 %0, %1, %2" : "=v"(W0) : "v"(w0), "v"(w1));
    asm("v_cvt_pk_bf16_f32 %0, %1, %2" : "=v"(W1) : "v"(w2), "v"(w3));
    int kk = in ? (k - 3) : 99;                  // sentinel -> all-zero row
    unsigned odd = (unsigned)kk & 1u;
    unsigned A = W0 << 16;
    unsigned B = (W0 >> 16) | (W1 << 16);
    unsigned C = W1 >> 16;
    unsigned t0 = odd ? A : W0;
    unsigned t1 = odd ? B : W1;
    unsigned t2 = odd ? C : 0u;
    int q = kk >> 1;                             // arithmetic: floor((k-3)/2)
    uint4 pk;
    pk.x = (q == 0) ? t0 : (q == -1) ? t1 : (q == -2) ? t2 : 0u;
    pk.y = (q == 1) ? t0 : (q == 0)  ? t1 : (q == -1) ? t2 : 0u;
    pk.z = (q == 2) ? t0 : (q == 1)  ? t1 : (q == 0)  ? t2 : 0u;
    pk.w = (q == 3) ? t0 : (q == 2)  ? t1 : (q == 1)  ? t2 : 0u;
    int key = (p >> 1) & 3;
    *reinterpret_cast<uint4*>(spl + p * 64 + ((ch ^ key) << 4)) = pk;
    *reinterpret_cast<unsigned short*>(
        slu + p * 64 + (((cg >> 3) ^ key) << 4) + ((cg * 2) & 15)) =
        (unsigned short)bf16r(sv);
}

// ---- layer 2: 3x3 grouped KAN conv via bf16 MFMA implicit GEMM ----
// block: (b,g,16x16 tile), 4 waves; wave -> 4 output rows x 32 co.
// + fused BN partial sums (deterministic) written to partial2[blk][64].
__global__ void __launch_bounds__(256) kan2_mfma2_kernel(
    const float* __restrict__ h1, const bf16x8* __restrict__ wfs,
    const bf16x8* __restrict__ wfb, const float* __restrict__ bb2,
    float* __restrict__ h2, float* __restrict__ partial2) {
    __shared__ __align__(16) unsigned char lds[41472];
    unsigned char* spl = lds;            // 20736 B
    unsigned char* slu = lds + 20736;    // 20736 B

    const int tid = threadIdx.x;
    const int lane = tid & 63;
    const int w = tid >> 6;
    const int blk = blockIdx.x;
    const int tile = blk & 15;
    const int g = (blk >> 4) & 7;
    const int b = blk >> 7;
    const int ty = (tile >> 2) * 16, tx = (tile & 3) * 16;
    const int lrow = lane & 15;
    const int lhi = lane >> 4;

    // per-thread halo coords (hoists /18 out of the staging loop)
    const int hy0 = tid / 18;
    const int hx0 = tid - hy0 * 18;
    const int tpb = tid + 256;           // second pass, threads < 68
    const int hyb = tpb / 18;
    const int hxb = tpb - hyb * 18;

    f32x4 acc[4][2];
#pragma unroll
    for (int y = 0; y < 4; ++y)
#pragma unroll
        for (int nf = 0; nf < 2; ++nf) {
            float bias = bb2[g * 32 + nf * 16 + lrow];
            acc[y][nf] = (f32x4){bias, bias, bias, bias};
        }

    const float* h1g = h1 + (size_t)(b * COUT + g * 32) * HW;
    const int hybase = w * 4;

    for (int cc = 0; cc < 8; ++cc) {
        __syncthreads();
#pragma unroll
        for (int ch = 0; ch < 4; ++ch) {
            const float* h1c = h1g + (size_t)(cc * 4 + ch) * HW;
            stage_one(h1c, spl, slu, tid, hy0, hx0, ty, tx, ch, cc * 4 + ch);
            if (tid < 68)
                stage_one(h1c, spl, slu, tpb, hyb, hxb, ty, tx, ch, cc * 4 + ch);
        }
        __syncthreads();
        // spline MFMAs: K=32 = 4ch x 8basis; dy-reuse of each A-read
#pragma unroll
        for (int dx = 0; dx < 3; ++dx) {
            bf16x8 bf[3][2];
            const bf16x8* wp = wfs + (size_t)((((g * 8 + cc) * 3 + dx) * 3) * 2) * 64;
#pragma unroll
            for (int dy = 0; dy < 3; ++dy)
#pragma unroll
                for (int nf = 0; nf < 2; ++nf)
                    bf[dy][nf] = wp[(dy * 2 + nf) * 64 + lane];
#pragma unroll
            for (int hr = 0; hr < 6; ++hr) {
                int p = (hybase + hr) * 18 + lrow + dx;
                int ra = p * 64 + (((lhi ^ ((p >> 1) & 3))) << 4);
                bf16x8 af = *reinterpret_cast<const bf16x8*>(spl + ra);
#pragma unroll
                for (int dy = 0; dy < 3; ++dy) {
                    int y = hr - dy;
                    if (y >= 0 && y < 4) {
                        acc[y][0] = __builtin_amdgcn_mfma_f32_16x16x32_bf16(af, bf[dy][0], acc[y][0], 0, 0, 0);
                        acc[y][1] = __builtin_amdgcn_mfma_f32_16x16x32_bf16(af, bf[dy][1], acc[y][1], 0, 0, 0);
                    }
                }
            }
        }
    }
    // base branch: silu plane, K = 32 channels (k = lhi*8 + j)
#pragma unroll
    for (int dx = 0; dx < 3; ++dx) {
        bf16x8 bf[3][2];
        const bf16x8* wp = wfb + (size_t)(((g * 3 + dx) * 3) * 2) * 64;
#pragma unroll
        for (int dy = 0; dy < 3; ++dy)
#pragma unroll
            for (int nf = 0; nf < 2; ++nf)
                bf[dy][nf] = wp[(dy * 2 + nf) * 64 + lane];
#pragma unroll
        for (int hr = 0; hr < 6; ++hr) {
            int p = (hybase + hr) * 18 + lrow + dx;
            int ra = p * 64 + (((lhi ^ ((p >> 1) & 3))) << 4);
            bf16x8 af = *reinterpret_cast<const bf16x8*>(slu + ra);
#pragma unroll
            for (int dy = 0; dy < 3; ++dy) {
                int y = hr - dy;
                if (y >= 0 && y < 4) {
                    acc[y][0] = __builtin_amdgcn_mfma_f32_16x16x32_bf16(af, bf[dy][0], acc[y][0], 0, 0, 0);
                    acc[y][1] = __builtin_amdgcn_mfma_f32_16x16x32_bf16(af, bf[dy][1], acc[y][1], 0, 0, 0);
                }
            }
        }
    }
    // write: D row (m) = x = lhi*4 + reg, col (n) = co = lrow
#pragma unroll
    for (int y = 0; y < 4; ++y) {
        int oy = ty + w * 4 + y;
#pragma unroll
        for (int nf = 0; nf < 2; ++nf) {
            int co = g * 32 + nf * 16 + lrow;
            float4 o = {acc[y][nf][0], acc[y][nf][1], acc[y][nf][2], acc[y][nf][3]};
            *reinterpret_cast<float4*>(
                &h2[(((size_t)b * COUT + co) * 64 + oy) * 64 + tx + lhi * 4]) = o;
        }
    }
    // ---- fused BN partial sums (deterministic) ----
    float s0 = 0.0f, q0 = 0.0f, s1 = 0.0f, q1 = 0.0f;
#pragma unroll
    for (int y = 0; y < 4; ++y)
#pragma unroll
        for (int i = 0; i < 4; ++i) {
            float a0 = acc[y][0][i], a1 = acc[y][1][i];
            s0 += a0; q0 = fmaf(a0, a0, q0);
            s1 += a1; q1 = fmaf(a1, a1, q1);
        }
    s0 += __shfl_xor(s0, 16); s0 += __shfl_xor(s0, 32);
    q0 += __shfl_xor(q0, 16); q0 += __shfl_xor(q0, 32);
    s1 += __shfl_xor(s1, 16); s1 += __shfl_xor(s1, 32);
    q1 += __shfl_xor(q1, 16); q1 += __shfl_xor(q1, 32);
    __syncthreads();                     // all waves done with LDS
    float* stb = reinterpret_cast<float*>(lds);
    if (lane < 16) {
        int base = (w * 16 + lane) * 4;
        stb[base] = s0; stb[base + 1] = q0;
        stb[base + 2] = s1; stb[base + 3] = q1;
    }
    __syncthreads();
    if (tid < 64) {
        int slot = tid >> 1;             // nf*16 + lrow
        int j = tid & 1;
        int lr = slot & 15, nf = slot >> 4;
        float a = 0.0f;
#pragma unroll
        for (int wv = 0; wv < 4; ++wv)
            a += stb[(wv * 16 + lr) * 4 + nf * 2 + j];
        partial2[blk * 64 + tid] = a;
    }
}

// ---- BN stats: one block per channel, reduce 256 block-partials ----
__global__ void __launch_bounds__(256) bnstat2_kernel(
    const float* __restrict__ partial2, const float* __restrict__ gamma,
    const float* __restrict__ beta, float* __restrict__ stats) {
    int co = blockIdx.x;
    int t = threadIdx.x;
    int g = co >> 5, loc = co & 31;
    int b = t >> 4, tile = t & 15;
    int blk = (b * 8 + g) * 16 + tile;
    float s = partial2[blk * 64 + loc * 2];
    float ss = partial2[blk * 64 + loc * 2 + 1];
    __shared__ float r1[256], r2[256];
    r1[t] = s; r2[t] = ss;
    __syncthreads();
    for (int o = 128; o > 0; o >>= 1) {
        if (t < o) { r1[t] += r1[t + o]; r2[t] += r2[t + o]; }
        __syncthreads();
    }
    if (t == 0) {
        const float invn = 1.0f / 65536.0f;
        float mean = r1[0] * invn;
        float var = r2[0] * invn - mean * mean;
        float sc = gamma[co] * rsqrtf(var + 1e-5f);
        stats[2 * co] = sc;
        stats[2 * co + 1] = beta[co] - mean * sc;
    }
}

// ---- BN apply (in place on d_out) ----
__global__ void __launch_bounds__(256) bnapply_kernel(
    float* __restrict__ h2, const float* __restrict__ stats, int n4) {
    int i = blockIdx.x * 256 + threadIdx.x;
    if (i >= n4) return;
    int co = (i >> 10) & 255;
    float sc = stats[2 * co], sh = stats[2 * co + 1];
    float4 v = reinterpret_cast<float4*>(h2)[i];
    float4 o;
    o.x = fmaf(v.x, sc, sh);
    o.y = fmaf(v.y, sc, sh);
    o.z = fmaf(v.z, sc, sh);
    o.w = fmaf(v.w, sc, sh);
    reinterpret_cast<float4*>(h2)[i] = o;
}

extern "C" void kernel_launch(void* const* d_in, const int* in_sizes, int n_in,
                              void* d_out, int out_size, void* d_ws, size_t ws_size,
                              hipStream_t stream) {
    const float* x   = (const float*)d_in[0];
    const float* wb1 = (const float*)d_in[1];
    const float* bb1 = (const float*)d_in[2];
    const float* ws1 = (const float*)d_in[3];
    const float* wb2 = (const float*)d_in[4];
    const float* bb2 = (const float*)d_in[5];
    const float* ws2 = (const float*)d_in[6];
    const float* gamma = (const float*)d_in[7];
    const float* beta  = (const float*)d_in[8];

    char* ws = (char*)d_ws;
    float* wp1 = (float*)ws;                                 // 147,456 B
    unsigned short* wfs = (unsigned short*)(ws + 147456);    // 1,179,648 B
    unsigned short* wfb = (unsigned short*)(ws + 1327104);   // 147,456 B
    float* partial2 = (float*)(ws + 1474560);                // 524,288 B
    float* stats    = (float*)(ws + 1998848);                // 2,048 B
    float* h1       = (float*)(ws + 2000896);                // 67,108,864 B

    float* h2 = (float*)d_out;   // conv2 output in d_out; BN in-place

    repack2_kernel<<<(WFS_ELEMS + 255) / 256, 256, 0, stream>>>(
        wb1, ws1, wb2, ws2, wp1, wfs, wfb);
    kan1_kernel<<<BATCH * GROUPS * 16, 256, 0, stream>>>(x, wp1, bb1, h1);
    kan2_mfma2_kernel<<<BATCH * GROUPS * 16, 256, 0, stream>>>(
        h1, (const bf16x8*)wfs, (const bf16x8*)wfb, bb2, h2, partial2);
    bnstat2_kernel<<<COUT, 256, 0, stream>>>(partial2, gamma, beta, stats);
    bnapply_kernel<<<(4194304 + 255) / 256, 256, 0, stream>>>(
        h2, stats, 4194304);
}

// Round 8
// 213.450 us; speedup vs baseline: 2.8028x; 1.2786x over previous
//
#include <hip/hip_runtime.h>
#include <hip/hip_bf16.h>
#include <stdint.h>

// GSC_kan: two grouped KAN convs (1x1, 3x3; G=8) + BatchNorm.
// Round 8: kan2 was latency-bound (MfmaUtil 21 + VALUBusy 37, neither
// saturated). T14 async-stage split: h1 loads issued one chunk ahead into
// regs; wfs B-frags software-pipelined one dx ahead; staging balanced via
// precomputed magic-divide descriptors. __launch_bounds__(256,3) keeps
// 3 blocks/CU (LDS-capped) while allowing prefetch VGPRs.

#define NB 8
#define NF 9
#define CIN 128
#define COUT 256
#define GROUPS 8
#define HW 4096
#define BATCH 16

#define WFS_ELEMS 589824   // 256 * 32 * 8 * 9
#define WFB_ELEMS 73728    // 256 * 32 * 9

typedef __attribute__((ext_vector_type(8))) short bf16x8;
typedef __attribute__((ext_vector_type(4))) float f32x4;

__device__ __forceinline__ unsigned bf16r(float f) {
    union { float f; unsigned u; } c; c.f = f;
    unsigned r = c.u + 0x7FFF + ((c.u >> 16) & 1);   // RNE
    return r >> 16;
}

// uniform-knot cubic B-spline: 4 nonzero cardinal weights at interval k.
// knots t_j = -1 + (j-3)*0.4 (j=0..11); s=(v+2.2)*2.5; nonzero bases k-3..k.
__device__ __forceinline__ void spline_w(float v, float& w0, float& w1,
                                         float& w2, float& w3, int& k) {
    float s = (v + 2.2f) * 2.5f;
    float fk = floorf(s);
    k = (int)fk;
    float u = s - fk;
    float um = 1.0f - u;
    float u2 = u * u, u3 = u2 * u;
    w0 = um * um * um * (1.0f / 6.0f);
    w1 = (3.0f * u3 - 6.0f * u2 + 4.0f) * (1.0f / 6.0f);
    w2 = (-3.0f * u3 + 3.0f * u2 + 3.0f * u + 1.0f) * (1.0f / 6.0f);
    w3 = u3 * (1.0f / 6.0f);
}

__device__ __forceinline__ void kan_features_fast(float v, float* __restrict__ f) {
    f[0] = v / (1.0f + __expf(-v));
    float w0, w1, w2, w3; int k;
    spline_w(v, w0, w1, w2, w3, k);
#pragma unroll
    for (int idx = 0; idx < 8; ++idx) {
        int d = idx - k + 3;
        float r = (d == 0) ? w0 : 0.0f;
        r = (d == 1) ? w1 : r;
        r = (d == 2) ? w2 : r;
        r = (d == 3) ? w3 : r;
        f[1 + idx] = r;
    }
}

// ---- repack: wp1 fp32 [g][c16][f9][co32]; wfs/wfb bf16 B-fragment layouts ----
__global__ void __launch_bounds__(256) repack2_kernel(
    const float* __restrict__ wb1, const float* __restrict__ ws1,
    const float* __restrict__ wb2, const float* __restrict__ ws2,
    float* __restrict__ wp1, unsigned short* __restrict__ wfs,
    unsigned short* __restrict__ wfb) {
    int i = blockIdx.x * 256 + threadIdx.x;
    if (i < 8 * 16 * 9 * 32) {
        int co = i & 31;
        int t = i >> 5;
        int f = t % 9; t /= 9;
        int c = t & 15; int g = t >> 4;
        int cog = g * 32 + co;
        wp1[i] = (f == 0) ? wb1[cog * 16 + c]
                          : ws1[cog * 128 + c * 8 + (f - 1)];
    }
    if (i < WFB_ELEMS) {
        int j = i & 7;
        int lane = (i >> 3) & 63;
        int nf = (i >> 9) & 1;
        int t = i >> 10;
        int dy = t % 3; t /= 3;
        int dx = t % 3; t /= 3;
        int g = t;
        int ch = (lane >> 4) * 8 + j;
        int cog = g * 32 + nf * 16 + (lane & 15);
        wfb[i] = (unsigned short)bf16r(wb2[((cog * 32 + ch) * 3 + dy) * 3 + dx]);
    }
    if (i < WFS_ELEMS) {
        int j = i & 7;
        int t = i >> 3;
        int lane = t & 63; t >>= 6;
        int nf = t & 1; t >>= 1;
        int dy = t % 3; t /= 3;
        int dx = t % 3; t /= 3;
        int cc = t & 7; t >>= 3;
        int g = t;
        int c_loc = cc * 4 + (lane >> 4);
        int cog = g * 32 + nf * 16 + (lane & 15);
        float v = ws2[((cog * 256 + c_loc * 8 + j) * 3 + dy) * 3 + dx];
        wfs[i] = (unsigned short)bf16r(v);
    }
}

// ---- layer 1: 1x1 grouped KAN conv (fp32 VALU) ----
__global__ void __launch_bounds__(256) kan1_kernel(
    const float* __restrict__ x, const float* __restrict__ wp1,
    const float* __restrict__ bb1, float* __restrict__ h1) {
    int tid = threadIdx.x;
    int blk = blockIdx.x;
    int t = blk & 15;
    int g = (blk >> 4) & 7;
    int b = blk >> 7;
    int pos = t * 256 + tid;

    float acc[32];
    const float* bb = bb1 + g * 32;
#pragma unroll
    for (int co = 0; co < 32; ++co) acc[co] = bb[co];

    for (int c = 0; c < 16; ++c) {
        float v = x[(b * CIN + g * 16 + c) * HW + pos];
        float ft[NF];
        kan_features_fast(v, ft);
        const float* wp = wp1 + ((g * 16 + c) * 9) * 32;
        for (int f = 0; f < NF; ++f) {
            float fv = ft[f];
#pragma unroll
            for (int co = 0; co < 32; ++co)
                acc[co] = fmaf(wp[f * 32 + co], fv, acc[co]);
        }
    }
    float* op = h1 + (b * COUT + g * 32) * HW + pos;
#pragma unroll
    for (int co = 0; co < 32; ++co) op[co * HW] = acc[co];
}

// ---- stage one element from a pre-loaded register value ----
__device__ __forceinline__ void stage_elem(
    unsigned char* __restrict__ spl, unsigned char* __restrict__ slu,
    float v, bool in, int waddrS, int p, int cg) {
    float sv = v / (1.0f + __expf(-v));
    float w0, w1, w2, w3; int k;
    spline_w(v, w0, w1, w2, w3, k);
    unsigned W0, W1;
    asm("v_cvt_pk_bf16_f32 %0, %1, %2" : "=v"(W0) : "v"(w0), "v"(w1));
    asm("v_cvt_pk_bf16_f32 %0, %1, %2" : "=v"(W1) : "v"(w2), "v"(w3));
    int kk = in ? (k - 3) : 99;                  // sentinel -> all-zero row
    unsigned odd = (unsigned)kk & 1u;
    unsigned A = W0 << 16;
    unsigned B = (W0 >> 16) | (W1 << 16);
    unsigned C = W1 >> 16;
    unsigned t0 = odd ? A : W0;
    unsigned t1 = odd ? B : W1;
    unsigned t2 = odd ? C : 0u;
    int q = kk >> 1;                             // floor((k-3)/2)
    uint4 pk;
    pk.x = (q == 0) ? t0 : (q == -1) ? t1 : (q == -2) ? t2 : 0u;
    pk.y = (q == 1) ? t0 : (q == 0)  ? t1 : (q == -1) ? t2 : 0u;
    pk.z = (q == 2) ? t0 : (q == 1)  ? t1 : (q == 0)  ? t2 : 0u;
    pk.w = (q == 3) ? t0 : (q == 2)  ? t1 : (q == 1)  ? t2 : 0u;
    *reinterpret_cast<uint4*>(spl + waddrS) = pk;
    int key = (p >> 1) & 3;
    *reinterpret_cast<unsigned short*>(
        slu + p * 64 + (((cg >> 3) ^ key) << 4) + ((cg * 2) & 15)) =
        (unsigned short)bf16r(sv);
}

// ---- MFMA over one dx tap-column, dy-reused A-reads ----
__device__ __forceinline__ void mfma_hr(
    const unsigned char* __restrict__ spl, const bf16x8 (&bf)[3][2],
    int pbase, int lhi, f32x4 (&acc)[4][2]) {
#pragma unroll
    for (int hr = 0; hr < 6; ++hr) {
        int p = pbase + hr * 18;
        int ra = p * 64 + ((lhi ^ ((p >> 1) & 3)) << 4);
        bf16x8 af = *reinterpret_cast<const bf16x8*>(spl + ra);
#pragma unroll
        for (int dy = 0; dy < 3; ++dy) {
            int y = hr - dy;
            if (y >= 0 && y < 4) {
                acc[y][0] = __builtin_amdgcn_mfma_f32_16x16x32_bf16(af, bf[dy][0], acc[y][0], 0, 0, 0);
                acc[y][1] = __builtin_amdgcn_mfma_f32_16x16x32_bf16(af, bf[dy][1], acc[y][1], 0, 0, 0);
            }
        }
    }
}

// ---- layer 2: 3x3 grouped KAN conv via bf16 MFMA, async-staged ----
__global__ void __launch_bounds__(256, 3) kan2_mfma3_kernel(
    const float* __restrict__ h1, const bf16x8* __restrict__ wfs,
    const bf16x8* __restrict__ wfb, const float* __restrict__ bb2,
    float* __restrict__ h2, float* __restrict__ partial2) {
    __shared__ __align__(16) unsigned char lds[41472];
    unsigned char* spl = lds;            // 20736 B
    unsigned char* slu = lds + 20736;    // 20736 B

    const int tid = threadIdx.x;
    const int lane = tid & 63;
    const int w = tid >> 6;
    const int blk = blockIdx.x;
    const int tile = blk & 15;
    const int g = (blk >> 4) & 7;
    const int b = blk >> 7;
    const int ty = (tile >> 2) * 16, tx = (tile & 3) * 16;
    const int lrow = lane & 15;
    const int lhi = lane >> 4;

    // ---- staging descriptors: 1296 = 4ch x 324 halo, balanced over threads
    int chv[6], pv[6], offv[6], wadS[6];
#pragma unroll
    for (int it = 0; it < 6; ++it) {
        int e = tid + it * 256;
        int ch = (e * 3237) >> 20;       // e/324 for e<1296
        int p = e - ch * 324;
        int hy = (p * 57) >> 10;         // p/18 for p<324
        int hx = p - hy * 18;
        int iy = ty + hy - 1, ix = tx + hx - 1;
        bool in = ((unsigned)iy < 64u) & ((unsigned)ix < 64u);
        chv[it] = ch;
        pv[it] = p;
        offv[it] = in ? (iy * 64 + ix) : -1;
        int key = (p >> 1) & 3;
        wadS[it] = p * 64 + ((ch ^ key) << 4);
    }

    const float* h1g = h1 + (size_t)(b * COUT + g * 32) * HW;

    // prologue: issue loads for chunk 0
    float vreg[6];
#pragma unroll
    for (int it = 0; it < 6; ++it) {
        if (it < 5 || tid < 16)
            vreg[it] = (offv[it] >= 0) ? h1g[chv[it] * HW + offv[it]] : 0.0f;
    }

    f32x4 acc[4][2];
#pragma unroll
    for (int y = 0; y < 4; ++y)
#pragma unroll
        for (int nf = 0; nf < 2; ++nf) {
            float bias = bb2[g * 32 + nf * 16 + lrow];
            acc[y][nf] = (f32x4){bias, bias, bias, bias};
        }

    const int pbase0 = (w * 4) * 18 + lrow;

    for (int cc = 0; cc < 8; ++cc) {
        // preload dx=0 B-frags (in flight across stage phase)
        const bf16x8* wpc = wfs + (size_t)((g * 8 + cc) * 18) * 64;
        bf16x8 bfA[3][2];
#pragma unroll
        for (int dy = 0; dy < 3; ++dy)
#pragma unroll
            for (int nf = 0; nf < 2; ++nf)
                bfA[dy][nf] = wpc[(dy * 2 + nf) * 64 + lane];

        __syncthreads();                 // spl free (prev MFMA done)
        // stage chunk cc from registers (pure VALU + ds_write)
#pragma unroll
        for (int it = 0; it < 6; ++it) {
            if (it < 5 || tid < 16)
                stage_elem(spl, slu, vreg[it], offv[it] >= 0, wadS[it],
                           pv[it], cc * 4 + chv[it]);
        }
        // issue loads for chunk cc+1 (hidden under barrier + MFMA phase)
        if (cc < 7) {
#pragma unroll
            for (int it = 0; it < 6; ++it) {
                if (it < 5 || tid < 16)
                    vreg[it] = (offv[it] >= 0)
                        ? h1g[((cc + 1) * 4 + chv[it]) * HW + offv[it]] : 0.0f;
            }
        }
        __syncthreads();                 // staging complete

        // MFMA phase, B-frags pipelined one dx ahead
#pragma unroll
        for (int dx = 0; dx < 3; ++dx) {
            bf16x8 bfB[3][2];
            if (dx < 2) {
                const bf16x8* wpn = wpc + (size_t)((dx + 1) * 6) * 64;
#pragma unroll
                for (int dy = 0; dy < 3; ++dy)
#pragma unroll
                    for (int nf = 0; nf < 2; ++nf)
                        bfB[dy][nf] = wpn[(dy * 2 + nf) * 64 + lane];
            }
            mfma_hr(spl, bfA, pbase0 + dx, lhi, acc);
            if (dx < 2) {
#pragma unroll
                for (int dy = 0; dy < 3; ++dy)
#pragma unroll
                    for (int nf = 0; nf < 2; ++nf)
                        bfA[dy][nf] = bfB[dy][nf];
            }
        }
    }

    // base branch: silu plane, K = 32 channels
#pragma unroll
    for (int dx = 0; dx < 3; ++dx) {
        bf16x8 bf[3][2];
        const bf16x8* wp = wfb + (size_t)(((g * 3 + dx) * 3) * 2) * 64;
#pragma unroll
        for (int dy = 0; dy < 3; ++dy)
#pragma unroll
            for (int nf = 0; nf < 2; ++nf)
                bf[dy][nf] = wp[(dy * 2 + nf) * 64 + lane];
        mfma_hr(slu, bf, pbase0 + dx, lhi, acc);
    }

    // write: D row (m) = x = lhi*4 + reg, col (n) = co = lrow
#pragma unroll
    for (int y = 0; y < 4; ++y) {
        int oy = ty + w * 4 + y;
#pragma unroll
        for (int nf = 0; nf < 2; ++nf) {
            int co = g * 32 + nf * 16 + lrow;
            float4 o = {acc[y][nf][0], acc[y][nf][1], acc[y][nf][2], acc[y][nf][3]};
            *reinterpret_cast<float4*>(
                &h2[(((size_t)b * COUT + co) * 64 + oy) * 64 + tx + lhi * 4]) = o;
        }
    }

    // ---- fused BN partial sums (deterministic) ----
    float s0 = 0.0f, q0 = 0.0f, s1 = 0.0f, q1 = 0.0f;
#pragma unroll
    for (int y = 0; y < 4; ++y)
#pragma unroll
        for (int i = 0; i < 4; ++i) {
            float a0 = acc[y][0][i], a1 = acc[y][1][i];
            s0 += a0; q0 = fmaf(a0, a0, q0);
            s1 += a1; q1 = fmaf(a1, a1, q1);
        }
    s0 += __shfl_xor(s0, 16); s0 += __shfl_xor(s0, 32);
    q0 += __shfl_xor(q0, 16); q0 += __shfl_xor(q0, 32);
    s1 += __shfl_xor(s1, 16); s1 += __shfl_xor(s1, 32);
    q1 += __shfl_xor(q1, 16); q1 += __shfl_xor(q1, 32);
    __syncthreads();                     // all waves done with LDS
    float* stb = reinterpret_cast<float*>(lds);
    if (lane < 16) {
        int base = (w * 16 + lane) * 4;
        stb[base] = s0; stb[base + 1] = q0;
        stb[base + 2] = s1; stb[base + 3] = q1;
    }
    __syncthreads();
    if (tid < 64) {
        int slot = tid >> 1;
        int j = tid & 1;
        int lr = slot & 15, nf = slot >> 4;
        float a = 0.0f;
#pragma unroll
        for (int wv = 0; wv < 4; ++wv)
            a += stb[(wv * 16 + lr) * 4 + nf * 2 + j];
        partial2[blk * 64 + tid] = a;
    }
}

// ---- BN stats: one block per channel, reduce 256 block-partials ----
__global__ void __launch_bounds__(256) bnstat2_kernel(
    const float* __restrict__ partial2, const float* __restrict__ gamma,
    const float* __restrict__ beta, float* __restrict__ stats) {
    int co = blockIdx.x;
    int t = threadIdx.x;
    int g = co >> 5, loc = co & 31;
    int b = t >> 4, tile = t & 15;
    int blk = (b * 8 + g) * 16 + tile;
    float s = partial2[blk * 64 + loc * 2];
    float ss = partial2[blk * 64 + loc * 2 + 1];
    __shared__ float r1[256], r2[256];
    r1[t] = s; r2[t] = ss;
    __syncthreads();
    for (int o = 128; o > 0; o >>= 1) {
        if (t < o) { r1[t] += r1[t + o]; r2[t] += r2[t + o]; }
        __syncthreads();
    }
    if (t == 0) {
        const float invn = 1.0f / 65536.0f;
        float mean = r1[0] * invn;
        float var = r2[0] * invn - mean * mean;
        float sc = gamma[co] * rsqrtf(var + 1e-5f);
        stats[2 * co] = sc;
        stats[2 * co + 1] = beta[co] - mean * sc;
    }
}

// ---- BN apply (in place on d_out) ----
__global__ void __launch_bounds__(256) bnapply_kernel(
    float* __restrict__ h2, const float* __restrict__ stats, int n4) {
    int i = blockIdx.x * 256 + threadIdx.x;
    if (i >= n4) return;
    int co = (i >> 10) & 255;
    float sc = stats[2 * co], sh = stats[2 * co + 1];
    float4 v = reinterpret_cast<float4*>(h2)[i];
    float4 o;
    o.x = fmaf(v.x, sc, sh);
    o.y = fmaf(v.y, sc, sh);
    o.z = fmaf(v.z, sc, sh);
    o.w = fmaf(v.w, sc, sh);
    reinterpret_cast<float4*>(h2)[i] = o;
}

extern "C" void kernel_launch(void* const* d_in, const int* in_sizes, int n_in,
                              void* d_out, int out_size, void* d_ws, size_t ws_size,
                              hipStream_t stream) {
    const float* x   = (const float*)d_in[0];
    const float* wb1 = (const float*)d_in[1];
    const float* bb1 = (const float*)d_in[2];
    const float* ws1 = (const float*)d_in[3];
    const float* wb2 = (const float*)d_in[4];
    const float* bb2 = (const float*)d_in[5];
    const float* ws2 = (const float*)d_in[6];
    const float* gamma = (const float*)d_in[7];
    const float* beta  = (const float*)d_in[8];

    char* ws = (char*)d_ws;
    float* wp1 = (float*)ws;                                 // 147,456 B
    unsigned short* wfs = (unsigned short*)(ws + 147456);    // 1,179,648 B
    unsigned short* wfb = (unsigned short*)(ws + 1327104);   // 147,456 B
    float* partial2 = (float*)(ws + 1474560);                // 524,288 B
    float* stats    = (float*)(ws + 1998848);                // 2,048 B
    float* h1       = (float*)(ws + 2000896);                // 67,108,864 B

    float* h2 = (float*)d_out;   // conv2 output in d_out; BN in-place

    repack2_kernel<<<(WFS_ELEMS + 255) / 256, 256, 0, stream>>>(
        wb1, ws1, wb2, ws2, wp1, wfs, wfb);
    kan1_kernel<<<BATCH * GROUPS * 16, 256, 0, stream>>>(x, wp1, bb1, h1);
    kan2_mfma3_kernel<<<BATCH * GROUPS * 16, 256, 0, stream>>>(
        h1, (const bf16x8*)wfs, (const bf16x8*)wfb, bb2, h2, partial2);
    bnstat2_kernel<<<COUT, 256, 0, stream>>>(partial2, gamma, beta, stats);
    bnapply_kernel<<<(4194304 + 255) / 256, 256, 0, stream>>>(
        h2, stats, 4194304);
}

// Round 10
// 157.501 us; speedup vs baseline: 3.7985x; 1.3552x over previous
//
#include <hip/hip_runtime.h>
#include <hip/hip_bf16.h>
#include <stdint.h>

// GSC_kan: two grouped KAN convs (1x1, 3x3; G=8) + BatchNorm.
// Round 10: resubmit of R9 (infra: UnresponsiveContainer, same pod as R3).
// kan1 -> bf16 MFMA implicit GEMM (kan1m), mirroring kan2's structure:
// cvt_pk staging, XOR-swizzled LDS, one-chunk-ahead prefetch. conv1 K=144 =
// 4 spline chunks (K=32) + 1 zero-padded silu chunk (K=32). kan2/BN as R8.

#define NB 8
#define NF 9
#define CIN 128
#define COUT 256
#define GROUPS 8
#define HW 4096
#define BATCH 16

#define WFS_ELEMS 589824   // 256 * 32 * 8 * 9
#define WFB_ELEMS 73728    // 256 * 32 * 9
#define WF1S_ELEMS 32768   // 8g * 4cc * 2nf * 64 * 8
#define WF1B_ELEMS 8192    // 8g * 2nf * 64 * 8

typedef __attribute__((ext_vector_type(8))) short bf16x8;
typedef __attribute__((ext_vector_type(4))) float f32x4;

__device__ __forceinline__ unsigned bf16r(float f) {
    union { float f; unsigned u; } c; c.f = f;
    unsigned r = c.u + 0x7FFF + ((c.u >> 16) & 1);   // RNE
    return r >> 16;
}

// uniform-knot cubic B-spline: 4 nonzero cardinal weights at interval k.
// knots t_j = -1 + (j-3)*0.4 (j=0..11); s=(v+2.2)*2.5; nonzero bases k-3..k.
__device__ __forceinline__ void spline_w(float v, float& w0, float& w1,
                                         float& w2, float& w3, int& k) {
    float s = (v + 2.2f) * 2.5f;
    float fk = floorf(s);
    k = (int)fk;
    float u = s - fk;
    float um = 1.0f - u;
    float u2 = u * u, u3 = u2 * u;
    w0 = um * um * um * (1.0f / 6.0f);
    w1 = (3.0f * u3 - 6.0f * u2 + 4.0f) * (1.0f / 6.0f);
    w2 = (-3.0f * u3 + 3.0f * u2 + 3.0f * u + 1.0f) * (1.0f / 6.0f);
    w3 = u3 * (1.0f / 6.0f);
}

// ---- build the 8-bf16 spline row (zeros except w0..w3 at kk..kk+3) ----
__device__ __forceinline__ uint4 spline_row(float v, bool in, float& sv) {
    sv = v / (1.0f + __expf(-v));
    float w0, w1, w2, w3; int k;
    spline_w(v, w0, w1, w2, w3, k);
    unsigned W0, W1;
    asm("v_cvt_pk_bf16_f32 %0, %1, %2" : "=v"(W0) : "v"(w0), "v"(w1));
    asm("v_cvt_pk_bf16_f32 %0, %1, %2" : "=v"(W1) : "v"(w2), "v"(w3));
    int kk = in ? (k - 3) : 99;                  // sentinel -> all-zero row
    unsigned odd = (unsigned)kk & 1u;
    unsigned A = W0 << 16;
    unsigned B = (W0 >> 16) | (W1 << 16);
    unsigned C = W1 >> 16;
    unsigned t0 = odd ? A : W0;
    unsigned t1 = odd ? B : W1;
    unsigned t2 = odd ? C : 0u;
    int q = kk >> 1;                             // floor((k-3)/2)
    uint4 pk;
    pk.x = (q == 0) ? t0 : (q == -1) ? t1 : (q == -2) ? t2 : 0u;
    pk.y = (q == 1) ? t0 : (q == 0)  ? t1 : (q == -1) ? t2 : 0u;
    pk.z = (q == 2) ? t0 : (q == 1)  ? t1 : (q == 0)  ? t2 : 0u;
    pk.w = (q == 3) ? t0 : (q == 2)  ? t1 : (q == 1)  ? t2 : 0u;
    return pk;
}

// ---- repack: wfs/wfb (kan2) and wf1s/wf1b (kan1) bf16 B-fragment layouts ----
__global__ void __launch_bounds__(256) repack2_kernel(
    const float* __restrict__ wb1, const float* __restrict__ ws1,
    const float* __restrict__ wb2, const float* __restrict__ ws2,
    unsigned short* __restrict__ wfs, unsigned short* __restrict__ wfb,
    unsigned short* __restrict__ wf1s, unsigned short* __restrict__ wf1b) {
    int i = blockIdx.x * 256 + threadIdx.x;
    if (i < WF1S_ELEMS) {   // [g][cc4][nf2][lane64][j8]
        int j = i & 7;
        int lane = (i >> 3) & 63;
        int nf = (i >> 9) & 1;
        int cc = (i >> 10) & 3;
        int g = i >> 12;
        int c_loc = cc * 4 + (lane >> 4);
        int cog = g * 32 + nf * 16 + (lane & 15);
        wf1s[i] = (unsigned short)bf16r(ws1[cog * 128 + c_loc * 8 + j]);
    }
    if (i < WF1B_ELEMS) {   // [g][nf2][lane64][j8], k=(lane>>4)*8+j, zero k>=16
        int j = i & 7;
        int lane = (i >> 3) & 63;
        int nf = (i >> 9) & 1;
        int g = (i >> 10) & 7;
        int k = (lane >> 4) * 8 + j;
        int cog = g * 32 + nf * 16 + (lane & 15);
        wf1b[i] = (k < 16) ? (unsigned short)bf16r(wb1[cog * 16 + k]) : 0;
    }
    if (i < WFB_ELEMS) {
        int j = i & 7;
        int lane = (i >> 3) & 63;
        int nf = (i >> 9) & 1;
        int t = i >> 10;
        int dy = t % 3; t /= 3;
        int dx = t % 3; t /= 3;
        int g = t;
        int ch = (lane >> 4) * 8 + j;
        int cog = g * 32 + nf * 16 + (lane & 15);
        wfb[i] = (unsigned short)bf16r(wb2[((cog * 32 + ch) * 3 + dy) * 3 + dx]);
    }
    if (i < WFS_ELEMS) {
        int j = i & 7;
        int t = i >> 3;
        int lane = t & 63; t >>= 6;
        int nf = t & 1; t >>= 1;
        int dy = t % 3; t /= 3;
        int dx = t % 3; t /= 3;
        int cc = t & 7; t >>= 3;
        int g = t;
        int c_loc = cc * 4 + (lane >> 4);
        int cog = g * 32 + nf * 16 + (lane & 15);
        float v = ws2[((cog * 256 + c_loc * 8 + j) * 3 + dy) * 3 + dx];
        wfs[i] = (unsigned short)bf16r(v);
    }
}

// ---- layer 1: 1x1 grouped KAN conv via bf16 MFMA ----
// block: (b,g, 256-pos tile), 4 waves; wave -> 4 m-frags x 32 co.
// K = 4 spline chunks (4ch x 8 bases) + 1 silu chunk (16ch + 16 zero).
__global__ void __launch_bounds__(256, 4) kan1m_kernel(
    const float* __restrict__ x, const bf16x8* __restrict__ wf1s,
    const bf16x8* __restrict__ wf1b, const float* __restrict__ bb1,
    float* __restrict__ h1) {
    __shared__ __align__(16) unsigned char lds[32768];
    unsigned char* spl = lds;            // 16384: [pos256][64B] swizzled
    unsigned char* slu = lds + 16384;    // 16384: [pos256][64B] K=32 (16ch+16z)

    const int tid = threadIdx.x;
    const int lane = tid & 63;
    const int w = tid >> 6;
    const int blk = blockIdx.x;          // (b*8+g)*16 + tile
    const int tile = blk & 15;
    const int g = (blk >> 4) & 7;
    const int b = blk >> 7;
    const int lrow = lane & 15;
    const int lhi = lane >> 4;
    const int posg0 = tile * 256;

    // zero the upper-K (k=16..31) slots of slu for own pos
    {
        int key = (tid >> 1) & 3;
        uint4 z = {0, 0, 0, 0};
        *reinterpret_cast<uint4*>(slu + tid * 64 + ((2 ^ key) << 4)) = z;
        *reinterpret_cast<uint4*>(slu + tid * 64 + ((3 ^ key) << 4)) = z;
    }

    const float* xg = x + ((size_t)b * CIN + g * 16) * HW + posg0;

    float xreg[4];
#pragma unroll
    for (int it = 0; it < 4; ++it) xreg[it] = xg[it * HW + tid];

    f32x4 acc[4][2];
#pragma unroll
    for (int m = 0; m < 4; ++m)
#pragma unroll
        for (int nf = 0; nf < 2; ++nf) {
            float bias = bb1[g * 32 + nf * 16 + lrow];
            acc[m][nf] = (f32x4){bias, bias, bias, bias};
        }

    for (int cc = 0; cc < 4; ++cc) {
        __syncthreads();                 // spl free
        int key = (tid >> 1) & 3;
#pragma unroll
        for (int it = 0; it < 4; ++it) {
            float sv;
            uint4 pk = spline_row(xreg[it], true, sv);
            *reinterpret_cast<uint4*>(spl + tid * 64 + ((it ^ key) << 4)) = pk;
            int cg = cc * 4 + it;        // silu k-slot 0..15
            *reinterpret_cast<unsigned short*>(
                slu + tid * 64 + (((cg >> 3) ^ key) << 4) + (cg & 7) * 2) =
                (unsigned short)bf16r(sv);
        }
        if (cc < 3) {
#pragma unroll
            for (int it = 0; it < 4; ++it)
                xreg[it] = xg[((cc + 1) * 4 + it) * HW + tid];
        }
        __syncthreads();                 // staging complete
        const bf16x8* wpc = wf1s + (size_t)((g * 4 + cc) * 2) * 64;
        bf16x8 bf0 = wpc[lane];
        bf16x8 bf1 = wpc[64 + lane];
#pragma unroll
        for (int m = 0; m < 4; ++m) {
            int pos = w * 64 + m * 16 + lrow;
            int ra = pos * 64 + ((lhi ^ ((pos >> 1) & 3)) << 4);
            bf16x8 af = *reinterpret_cast<const bf16x8*>(spl + ra);
            acc[m][0] = __builtin_amdgcn_mfma_f32_16x16x32_bf16(af, bf0, acc[m][0], 0, 0, 0);
            acc[m][1] = __builtin_amdgcn_mfma_f32_16x16x32_bf16(af, bf1, acc[m][1], 0, 0, 0);
        }
    }
    // silu phase (slu fully populated before last barrier)
    {
        const bf16x8* wpb = wf1b + (size_t)(g * 2) * 64;
        bf16x8 bf0 = wpb[lane];
        bf16x8 bf1 = wpb[64 + lane];
#pragma unroll
        for (int m = 0; m < 4; ++m) {
            int pos = w * 64 + m * 16 + lrow;
            int ra = pos * 64 + ((lhi ^ ((pos >> 1) & 3)) << 4);
            bf16x8 af = *reinterpret_cast<const bf16x8*>(slu + ra);
            acc[m][0] = __builtin_amdgcn_mfma_f32_16x16x32_bf16(af, bf0, acc[m][0], 0, 0, 0);
            acc[m][1] = __builtin_amdgcn_mfma_f32_16x16x32_bf16(af, bf1, acc[m][1], 0, 0, 0);
        }
    }
    // write h1: pos = posg0 + w*64 + m*16 + lhi*4 + r; co = g*32 + nf*16 + lrow
#pragma unroll
    for (int m = 0; m < 4; ++m)
#pragma unroll
        for (int nf = 0; nf < 2; ++nf) {
            int co = g * 32 + nf * 16 + lrow;
            float4 o = {acc[m][nf][0], acc[m][nf][1], acc[m][nf][2], acc[m][nf][3]};
            *reinterpret_cast<float4*>(
                &h1[((size_t)b * COUT + co) * HW + posg0 + w * 64 + m * 16 + lhi * 4]) = o;
        }
}

// ---- stage one element from a pre-loaded register value (kan2) ----
__device__ __forceinline__ void stage_elem(
    unsigned char* __restrict__ spl, unsigned char* __restrict__ slu,
    float v, bool in, int waddrS, int p, int cg) {
    float sv;
    uint4 pk = spline_row(v, in, sv);
    *reinterpret_cast<uint4*>(spl + waddrS) = pk;
    int key = (p >> 1) & 3;
    *reinterpret_cast<unsigned short*>(
        slu + p * 64 + (((cg >> 3) ^ key) << 4) + ((cg * 2) & 15)) =
        (unsigned short)bf16r(sv);
}

// ---- MFMA over one dx tap-column, dy-reused A-reads ----
__device__ __forceinline__ void mfma_hr(
    const unsigned char* __restrict__ spl, const bf16x8 (&bf)[3][2],
    int pbase, int lhi, f32x4 (&acc)[4][2]) {
#pragma unroll
    for (int hr = 0; hr < 6; ++hr) {
        int p = pbase + hr * 18;
        int ra = p * 64 + ((lhi ^ ((p >> 1) & 3)) << 4);
        bf16x8 af = *reinterpret_cast<const bf16x8*>(spl + ra);
#pragma unroll
        for (int dy = 0; dy < 3; ++dy) {
            int y = hr - dy;
            if (y >= 0 && y < 4) {
                acc[y][0] = __builtin_amdgcn_mfma_f32_16x16x32_bf16(af, bf[dy][0], acc[y][0], 0, 0, 0);
                acc[y][1] = __builtin_amdgcn_mfma_f32_16x16x32_bf16(af, bf[dy][1], acc[y][1], 0, 0, 0);
            }
        }
    }
}

// ---- layer 2: 3x3 grouped KAN conv via bf16 MFMA, async-staged ----
__global__ void __launch_bounds__(256, 3) kan2_mfma3_kernel(
    const float* __restrict__ h1, const bf16x8* __restrict__ wfs,
    const bf16x8* __restrict__ wfb, const float* __restrict__ bb2,
    float* __restrict__ h2, float* __restrict__ partial2) {
    __shared__ __align__(16) unsigned char lds[41472];
    unsigned char* spl = lds;            // 20736 B
    unsigned char* slu = lds + 20736;    // 20736 B

    const int tid = threadIdx.x;
    const int lane = tid & 63;
    const int w = tid >> 6;
    const int blk = blockIdx.x;
    const int tile = blk & 15;
    const int g = (blk >> 4) & 7;
    const int b = blk >> 7;
    const int ty = (tile >> 2) * 16, tx = (tile & 3) * 16;
    const int lrow = lane & 15;
    const int lhi = lane >> 4;

    // staging descriptors: 1296 = 4ch x 324 halo, balanced over threads
    int chv[6], pv[6], offv[6], wadS[6];
#pragma unroll
    for (int it = 0; it < 6; ++it) {
        int e = tid + it * 256;
        int ch = (e * 3237) >> 20;       // e/324 for e<1296
        int p = e - ch * 324;
        int hy = (p * 57) >> 10;         // p/18 for p<324
        int hx = p - hy * 18;
        int iy = ty + hy - 1, ix = tx + hx - 1;
        bool in = ((unsigned)iy < 64u) & ((unsigned)ix < 64u);
        chv[it] = ch;
        pv[it] = p;
        offv[it] = in ? (iy * 64 + ix) : -1;
        int key = (p >> 1) & 3;
        wadS[it] = p * 64 + ((ch ^ key) << 4);
    }

    const float* h1g = h1 + (size_t)(b * COUT + g * 32) * HW;

    float vreg[6];
#pragma unroll
    for (int it = 0; it < 6; ++it) {
        if (it < 5 || tid < 16)
            vreg[it] = (offv[it] >= 0) ? h1g[chv[it] * HW + offv[it]] : 0.0f;
    }

    f32x4 acc[4][2];
#pragma unroll
    for (int y = 0; y < 4; ++y)
#pragma unroll
        for (int nf = 0; nf < 2; ++nf) {
            float bias = bb2[g * 32 + nf * 16 + lrow];
            acc[y][nf] = (f32x4){bias, bias, bias, bias};
        }

    const int pbase0 = (w * 4) * 18 + lrow;

    for (int cc = 0; cc < 8; ++cc) {
        const bf16x8* wpc = wfs + (size_t)((g * 8 + cc) * 18) * 64;
        bf16x8 bfA[3][2];
#pragma unroll
        for (int dy = 0; dy < 3; ++dy)
#pragma unroll
            for (int nf = 0; nf < 2; ++nf)
                bfA[dy][nf] = wpc[(dy * 2 + nf) * 64 + lane];

        __syncthreads();
#pragma unroll
        for (int it = 0; it < 6; ++it) {
            if (it < 5 || tid < 16)
                stage_elem(spl, slu, vreg[it], offv[it] >= 0, wadS[it],
                           pv[it], cc * 4 + chv[it]);
        }
        if (cc < 7) {
#pragma unroll
            for (int it = 0; it < 6; ++it) {
                if (it < 5 || tid < 16)
                    vreg[it] = (offv[it] >= 0)
                        ? h1g[((cc + 1) * 4 + chv[it]) * HW + offv[it]] : 0.0f;
            }
        }
        __syncthreads();

#pragma unroll
        for (int dx = 0; dx < 3; ++dx) {
            bf16x8 bfB[3][2];
            if (dx < 2) {
                const bf16x8* wpn = wpc + (size_t)((dx + 1) * 6) * 64;
#pragma unroll
                for (int dy = 0; dy < 3; ++dy)
#pragma unroll
                    for (int nf = 0; nf < 2; ++nf)
                        bfB[dy][nf] = wpn[(dy * 2 + nf) * 64 + lane];
            }
            mfma_hr(spl, bfA, pbase0 + dx, lhi, acc);
            if (dx < 2) {
#pragma unroll
                for (int dy = 0; dy < 3; ++dy)
#pragma unroll
                    for (int nf = 0; nf < 2; ++nf)
                        bfA[dy][nf] = bfB[dy][nf];
            }
        }
    }

    // base branch: silu plane, K = 32 channels
#pragma unroll
    for (int dx = 0; dx < 3; ++dx) {
        bf16x8 bf[3][2];
        const bf16x8* wp = wfb + (size_t)(((g * 3 + dx) * 3) * 2) * 64;
#pragma unroll
        for (int dy = 0; dy < 3; ++dy)
#pragma unroll
            for (int nf = 0; nf < 2; ++nf)
                bf[dy][nf] = wp[(dy * 2 + nf) * 64 + lane];
        mfma_hr(slu, bf, pbase0 + dx, lhi, acc);
    }

    // write: D row (m) = x = lhi*4 + reg, col (n) = co = lrow
#pragma unroll
    for (int y = 0; y < 4; ++y) {
        int oy = ty + w * 4 + y;
#pragma unroll
        for (int nf = 0; nf < 2; ++nf) {
            int co = g * 32 + nf * 16 + lrow;
            float4 o = {acc[y][nf][0], acc[y][nf][1], acc[y][nf][2], acc[y][nf][3]};
            *reinterpret_cast<float4*>(
                &h2[(((size_t)b * COUT + co) * 64 + oy) * 64 + tx + lhi * 4]) = o;
        }
    }

    // fused BN partial sums (deterministic)
    float s0 = 0.0f, q0 = 0.0f, s1 = 0.0f, q1 = 0.0f;
#pragma unroll
    for (int y = 0; y < 4; ++y)
#pragma unroll
        for (int i = 0; i < 4; ++i) {
            float a0 = acc[y][0][i], a1 = acc[y][1][i];
            s0 += a0; q0 = fmaf(a0, a0, q0);
            s1 += a1; q1 = fmaf(a1, a1, q1);
        }
    s0 += __shfl_xor(s0, 16); s0 += __shfl_xor(s0, 32);
    q0 += __shfl_xor(q0, 16); q0 += __shfl_xor(q0, 32);
    s1 += __shfl_xor(s1, 16); s1 += __shfl_xor(s1, 32);
    q1 += __shfl_xor(q1, 16); q1 += __shfl_xor(q1, 32);
    __syncthreads();
    float* stb = reinterpret_cast<float*>(lds);
    if (lane < 16) {
        int base = (w * 16 + lane) * 4;
        stb[base] = s0; stb[base + 1] = q0;
        stb[base + 2] = s1; stb[base + 3] = q1;
    }
    __syncthreads();
    if (tid < 64) {
        int slot = tid >> 1;
        int j = tid & 1;
        int lr = slot & 15, nf = slot >> 4;
        float a = 0.0f;
#pragma unroll
        for (int wv = 0; wv < 4; ++wv)
            a += stb[(wv * 16 + lr) * 4 + nf * 2 + j];
        partial2[blk * 64 + tid] = a;
    }
}

// ---- BN stats: one block per channel, reduce 256 block-partials ----
__global__ void __launch_bounds__(256) bnstat2_kernel(
    const float* __restrict__ partial2, const float* __restrict__ gamma,
    const float* __restrict__ beta, float* __restrict__ stats) {
    int co = blockIdx.x;
    int t = threadIdx.x;
    int g = co >> 5, loc = co & 31;
    int b = t >> 4, tile = t & 15;
    int blk = (b * 8 + g) * 16 + tile;
    float s = partial2[blk * 64 + loc * 2];
    float ss = partial2[blk * 64 + loc * 2 + 1];
    __shared__ float r1[256], r2[256];
    r1[t] = s; r2[t] = ss;
    __syncthreads();
    for (int o = 128; o > 0; o >>= 1) {
        if (t < o) { r1[t] += r1[t + o]; r2[t] += r2[t + o]; }
        __syncthreads();
    }
    if (t == 0) {
        const float invn = 1.0f / 65536.0f;
        float mean = r1[0] * invn;
        float var = r2[0] * invn - mean * mean;
        float sc = gamma[co] * rsqrtf(var + 1e-5f);
        stats[2 * co] = sc;
        stats[2 * co + 1] = beta[co] - mean * sc;
    }
}

// ---- BN apply (in place on d_out) ----
__global__ void __launch_bounds__(256) bnapply_kernel(
    float* __restrict__ h2, const float* __restrict__ stats, int n4) {
    int i = blockIdx.x * 256 + threadIdx.x;
    if (i >= n4) return;
    int co = (i >> 10) & 255;
    float sc = stats[2 * co], sh = stats[2 * co + 1];
    float4 v = reinterpret_cast<float4*>(h2)[i];
    float4 o;
    o.x = fmaf(v.x, sc, sh);
    o.y = fmaf(v.y, sc, sh);
    o.z = fmaf(v.z, sc, sh);
    o.w = fmaf(v.w, sc, sh);
    reinterpret_cast<float4*>(h2)[i] = o;
}

extern "C" void kernel_launch(void* const* d_in, const int* in_sizes, int n_in,
                              void* d_out, int out_size, void* d_ws, size_t ws_size,
                              hipStream_t stream) {
    const float* x   = (const float*)d_in[0];
    const float* wb1 = (const float*)d_in[1];
    const float* bb1 = (const float*)d_in[2];
    const float* ws1 = (const float*)d_in[3];
    const float* wb2 = (const float*)d_in[4];
    const float* bb2 = (const float*)d_in[5];
    const float* ws2 = (const float*)d_in[6];
    const float* gamma = (const float*)d_in[7];
    const float* beta  = (const float*)d_in[8];

    char* ws = (char*)d_ws;
    unsigned short* wfs  = (unsigned short*)ws;              // 1,179,648 B
    unsigned short* wfb  = (unsigned short*)(ws + 1179648);  // 147,456 B
    unsigned short* wf1s = (unsigned short*)(ws + 1327104);  // 65,536 B
    unsigned short* wf1b = (unsigned short*)(ws + 1392640);  // 16,384 B
    float* partial2 = (float*)(ws + 1409024);                // 524,288 B
    float* stats    = (float*)(ws + 1933312);                // 2,048 B
    float* h1       = (float*)(ws + 1935360);                // 67,108,864 B

    float* h2 = (float*)d_out;   // conv2 output in d_out; BN in-place

    repack2_kernel<<<(WFS_ELEMS + 255) / 256, 256, 0, stream>>>(
        wb1, ws1, wb2, ws2, wfs, wfb, wf1s, wf1b);
    kan1m_kernel<<<BATCH * GROUPS * 16, 256, 0, stream>>>(
        x, (const bf16x8*)wf1s, (const bf16x8*)wf1b, bb1, h1);
    kan2_mfma3_kernel<<<BATCH * GROUPS * 16, 256, 0, stream>>>(
        h1, (const bf16x8*)wfs, (const bf16x8*)wfb, bb2, h2, partial2);
    bnstat2_kernel<<<COUT, 256, 0, stream>>>(partial2, gamma, beta, stats);
    bnapply_kernel<<<(4194304 + 255) / 256, 256, 0, stream>>>(
        h2, stats, 4194304);
}

// Round 11
// 156.559 us; speedup vs baseline: 3.8213x; 1.0060x over previous
//
#include <hip/hip_runtime.h>
#include <hip/hip_bf16.h>
#include <stdint.h>

// GSC_kan: two grouped KAN convs (1x1, 3x3; G=8) + BatchNorm.
// Round 11: kan2's barrier-locked stage section held ~65 VALU ops/element
// (expansion), idling the MFMA pipe (MfmaUtil 30% vs ~40us floor). Move
// expansion of chunk cc+1 into the MFMA phase of chunk cc (registers), so
// the inter-barrier section is only ds_writes. Loads prefetch 2 chunks
// ahead. s_setprio(1) around MFMA clusters (3 blocks/CU phase diversity).

#define NB 8
#define NF 9
#define CIN 128
#define COUT 256
#define GROUPS 8
#define HW 4096
#define BATCH 16

#define WFS_ELEMS 589824   // 256 * 32 * 8 * 9
#define WFB_ELEMS 73728    // 256 * 32 * 9
#define WF1S_ELEMS 32768   // 8g * 4cc * 2nf * 64 * 8
#define WF1B_ELEMS 8192    // 8g * 2nf * 64 * 8

typedef __attribute__((ext_vector_type(8))) short bf16x8;
typedef __attribute__((ext_vector_type(4))) float f32x4;

__device__ __forceinline__ unsigned bf16r(float f) {
    union { float f; unsigned u; } c; c.f = f;
    unsigned r = c.u + 0x7FFF + ((c.u >> 16) & 1);   // RNE
    return r >> 16;
}

// uniform-knot cubic B-spline: 4 nonzero cardinal weights at interval k.
// knots t_j = -1 + (j-3)*0.4 (j=0..11); s=(v+2.2)*2.5; nonzero bases k-3..k.
__device__ __forceinline__ void spline_w(float v, float& w0, float& w1,
                                         float& w2, float& w3, int& k) {
    float s = (v + 2.2f) * 2.5f;
    float fk = floorf(s);
    k = (int)fk;
    float u = s - fk;
    float um = 1.0f - u;
    float u2 = u * u, u3 = u2 * u;
    w0 = um * um * um * (1.0f / 6.0f);
    w1 = (3.0f * u3 - 6.0f * u2 + 4.0f) * (1.0f / 6.0f);
    w2 = (-3.0f * u3 + 3.0f * u2 + 3.0f * u + 1.0f) * (1.0f / 6.0f);
    w3 = u3 * (1.0f / 6.0f);
}

// ---- build the 8-bf16 spline row (zeros except w0..w3 at kk..kk+3) ----
__device__ __forceinline__ uint4 spline_row(float v, bool in, float& sv) {
    sv = v / (1.0f + __expf(-v));
    float w0, w1, w2, w3; int k;
    spline_w(v, w0, w1, w2, w3, k);
    unsigned W0, W1;
    asm("v_cvt_pk_bf16_f32 %0, %1, %2" : "=v"(W0) : "v"(w0), "v"(w1));
    asm("v_cvt_pk_bf16_f32 %0, %1, %2" : "=v"(W1) : "v"(w2), "v"(w3));
    int kk = in ? (k - 3) : 99;                  // sentinel -> all-zero row
    unsigned odd = (unsigned)kk & 1u;
    unsigned A = W0 << 16;
    unsigned B = (W0 >> 16) | (W1 << 16);
    unsigned C = W1 >> 16;
    unsigned t0 = odd ? A : W0;
    unsigned t1 = odd ? B : W1;
    unsigned t2 = odd ? C : 0u;
    int q = kk >> 1;                             // floor((k-3)/2)
    uint4 pk;
    pk.x = (q == 0) ? t0 : (q == -1) ? t1 : (q == -2) ? t2 : 0u;
    pk.y = (q == 1) ? t0 : (q == 0)  ? t1 : (q == -1) ? t2 : 0u;
    pk.z = (q == 2) ? t0 : (q == 1)  ? t1 : (q == 0)  ? t2 : 0u;
    pk.w = (q == 3) ? t0 : (q == 2)  ? t1 : (q == 1)  ? t2 : 0u;
    return pk;
}

__device__ __forceinline__ void expand_elem(float v, bool in,
                                            uint4& pk, unsigned& su) {
    float sv;
    pk = spline_row(v, in, sv);
    su = bf16r(sv);
}

// ---- repack: wfs/wfb (kan2) and wf1s/wf1b (kan1) bf16 B-fragment layouts ----
__global__ void __launch_bounds__(256) repack2_kernel(
    const float* __restrict__ wb1, const float* __restrict__ ws1,
    const float* __restrict__ wb2, const float* __restrict__ ws2,
    unsigned short* __restrict__ wfs, unsigned short* __restrict__ wfb,
    unsigned short* __restrict__ wf1s, unsigned short* __restrict__ wf1b) {
    int i = blockIdx.x * 256 + threadIdx.x;
    if (i < WF1S_ELEMS) {   // [g][cc4][nf2][lane64][j8]
        int j = i & 7;
        int lane = (i >> 3) & 63;
        int nf = (i >> 9) & 1;
        int cc = (i >> 10) & 3;
        int g = i >> 12;
        int c_loc = cc * 4 + (lane >> 4);
        int cog = g * 32 + nf * 16 + (lane & 15);
        wf1s[i] = (unsigned short)bf16r(ws1[cog * 128 + c_loc * 8 + j]);
    }
    if (i < WF1B_ELEMS) {   // [g][nf2][lane64][j8], k=(lane>>4)*8+j, zero k>=16
        int j = i & 7;
        int lane = (i >> 3) & 63;
        int nf = (i >> 9) & 1;
        int g = (i >> 10) & 7;
        int k = (lane >> 4) * 8 + j;
        int cog = g * 32 + nf * 16 + (lane & 15);
        wf1b[i] = (k < 16) ? (unsigned short)bf16r(wb1[cog * 16 + k]) : 0;
    }
    if (i < WFB_ELEMS) {
        int j = i & 7;
        int lane = (i >> 3) & 63;
        int nf = (i >> 9) & 1;
        int t = i >> 10;
        int dy = t % 3; t /= 3;
        int dx = t % 3; t /= 3;
        int g = t;
        int ch = (lane >> 4) * 8 + j;
        int cog = g * 32 + nf * 16 + (lane & 15);
        wfb[i] = (unsigned short)bf16r(wb2[((cog * 32 + ch) * 3 + dy) * 3 + dx]);
    }
    if (i < WFS_ELEMS) {
        int j = i & 7;
        int t = i >> 3;
        int lane = t & 63; t >>= 6;
        int nf = t & 1; t >>= 1;
        int dy = t % 3; t /= 3;
        int dx = t % 3; t /= 3;
        int cc = t & 7; t >>= 3;
        int g = t;
        int c_loc = cc * 4 + (lane >> 4);
        int cog = g * 32 + nf * 16 + (lane & 15);
        float v = ws2[((cog * 256 + c_loc * 8 + j) * 3 + dy) * 3 + dx];
        wfs[i] = (unsigned short)bf16r(v);
    }
}

// ---- layer 1: 1x1 grouped KAN conv via bf16 MFMA ----
__global__ void __launch_bounds__(256, 4) kan1m_kernel(
    const float* __restrict__ x, const bf16x8* __restrict__ wf1s,
    const bf16x8* __restrict__ wf1b, const float* __restrict__ bb1,
    float* __restrict__ h1) {
    __shared__ __align__(16) unsigned char lds[32768];
    unsigned char* spl = lds;            // 16384: [pos256][64B] swizzled
    unsigned char* slu = lds + 16384;    // 16384: [pos256][64B] K=32 (16ch+16z)

    const int tid = threadIdx.x;
    const int lane = tid & 63;
    const int w = tid >> 6;
    const int blk = blockIdx.x;          // (b*8+g)*16 + tile
    const int tile = blk & 15;
    const int g = (blk >> 4) & 7;
    const int b = blk >> 7;
    const int lrow = lane & 15;
    const int lhi = lane >> 4;
    const int posg0 = tile * 256;

    {
        int key = (tid >> 1) & 3;
        uint4 z = {0, 0, 0, 0};
        *reinterpret_cast<uint4*>(slu + tid * 64 + ((2 ^ key) << 4)) = z;
        *reinterpret_cast<uint4*>(slu + tid * 64 + ((3 ^ key) << 4)) = z;
    }

    const float* xg = x + ((size_t)b * CIN + g * 16) * HW + posg0;

    float xreg[4];
#pragma unroll
    for (int it = 0; it < 4; ++it) xreg[it] = xg[it * HW + tid];

    f32x4 acc[4][2];
#pragma unroll
    for (int m = 0; m < 4; ++m)
#pragma unroll
        for (int nf = 0; nf < 2; ++nf) {
            float bias = bb1[g * 32 + nf * 16 + lrow];
            acc[m][nf] = (f32x4){bias, bias, bias, bias};
        }

    for (int cc = 0; cc < 4; ++cc) {
        __syncthreads();
        int key = (tid >> 1) & 3;
#pragma unroll
        for (int it = 0; it < 4; ++it) {
            float sv;
            uint4 pk = spline_row(xreg[it], true, sv);
            *reinterpret_cast<uint4*>(spl + tid * 64 + ((it ^ key) << 4)) = pk;
            int cg = cc * 4 + it;
            *reinterpret_cast<unsigned short*>(
                slu + tid * 64 + (((cg >> 3) ^ key) << 4) + (cg & 7) * 2) =
                (unsigned short)bf16r(sv);
        }
        if (cc < 3) {
#pragma unroll
            for (int it = 0; it < 4; ++it)
                xreg[it] = xg[((cc + 1) * 4 + it) * HW + tid];
        }
        __syncthreads();
        const bf16x8* wpc = wf1s + (size_t)((g * 4 + cc) * 2) * 64;
        bf16x8 bf0 = wpc[lane];
        bf16x8 bf1 = wpc[64 + lane];
#pragma unroll
        for (int m = 0; m < 4; ++m) {
            int pos = w * 64 + m * 16 + lrow;
            int ra = pos * 64 + ((lhi ^ ((pos >> 1) & 3)) << 4);
            bf16x8 af = *reinterpret_cast<const bf16x8*>(spl + ra);
            acc[m][0] = __builtin_amdgcn_mfma_f32_16x16x32_bf16(af, bf0, acc[m][0], 0, 0, 0);
            acc[m][1] = __builtin_amdgcn_mfma_f32_16x16x32_bf16(af, bf1, acc[m][1], 0, 0, 0);
        }
    }
    {
        const bf16x8* wpb = wf1b + (size_t)(g * 2) * 64;
        bf16x8 bf0 = wpb[lane];
        bf16x8 bf1 = wpb[64 + lane];
#pragma unroll
        for (int m = 0; m < 4; ++m) {
            int pos = w * 64 + m * 16 + lrow;
            int ra = pos * 64 + ((lhi ^ ((pos >> 1) & 3)) << 4);
            bf16x8 af = *reinterpret_cast<const bf16x8*>(slu + ra);
            acc[m][0] = __builtin_amdgcn_mfma_f32_16x16x32_bf16(af, bf0, acc[m][0], 0, 0, 0);
            acc[m][1] = __builtin_amdgcn_mfma_f32_16x16x32_bf16(af, bf1, acc[m][1], 0, 0, 0);
        }
    }
#pragma unroll
    for (int m = 0; m < 4; ++m)
#pragma unroll
        for (int nf = 0; nf < 2; ++nf) {
            int co = g * 32 + nf * 16 + lrow;
            float4 o = {acc[m][nf][0], acc[m][nf][1], acc[m][nf][2], acc[m][nf][3]};
            *reinterpret_cast<float4*>(
                &h1[((size_t)b * COUT + co) * HW + posg0 + w * 64 + m * 16 + lhi * 4]) = o;
        }
}

// ---- stage write from pre-expanded registers: wadS encodes p and ch ----
__device__ __forceinline__ void stage_write(
    unsigned char* __restrict__ spl, unsigned char* __restrict__ slu,
    const uint4& pk, unsigned su, int wadS, int cc) {
    *reinterpret_cast<uint4*>(spl + wadS) = pk;
    int p = wadS >> 6;
    int key = (p >> 1) & 3;
    int ch = ((wadS >> 4) & 3) ^ key;
    int cg = cc * 4 + ch;
    *reinterpret_cast<unsigned short*>(
        slu + p * 64 + (((cg >> 3) ^ key) << 4) + ((cg * 2) & 15)) =
        (unsigned short)su;
}

// ---- MFMA over one dx tap-column, dy-reused A-reads ----
__device__ __forceinline__ void mfma_hr(
    const unsigned char* __restrict__ spl, const bf16x8 (&bf)[3][2],
    int pbase, int lhi, f32x4 (&acc)[4][2]) {
#pragma unroll
    for (int hr = 0; hr < 6; ++hr) {
        int p = pbase + hr * 18;
        int ra = p * 64 + ((lhi ^ ((p >> 1) & 3)) << 4);
        bf16x8 af = *reinterpret_cast<const bf16x8*>(spl + ra);
#pragma unroll
        for (int dy = 0; dy < 3; ++dy) {
            int y = hr - dy;
            if (y >= 0 && y < 4) {
                acc[y][0] = __builtin_amdgcn_mfma_f32_16x16x32_bf16(af, bf[dy][0], acc[y][0], 0, 0, 0);
                acc[y][1] = __builtin_amdgcn_mfma_f32_16x16x32_bf16(af, bf[dy][1], acc[y][1], 0, 0, 0);
            }
        }
    }
}

// ---- layer 2: 3x3 grouped KAN conv, expansion overlapped with MFMA ----
__global__ void __launch_bounds__(256, 3) kan2_mfma4_kernel(
    const float* __restrict__ h1, const bf16x8* __restrict__ wfs,
    const bf16x8* __restrict__ wfb, const float* __restrict__ bb2,
    float* __restrict__ h2, float* __restrict__ partial2) {
    __shared__ __align__(16) unsigned char lds[41472];
    unsigned char* spl = lds;            // 20736 B
    unsigned char* slu = lds + 20736;    // 20736 B

    const int tid = threadIdx.x;
    const int lane = tid & 63;
    const int w = tid >> 6;
    const int blk = blockIdx.x;
    const int tile = blk & 15;
    const int g = (blk >> 4) & 7;
    const int b = blk >> 7;
    const int ty = (tile >> 2) * 16, tx = (tile & 3) * 16;
    const int lrow = lane & 15;
    const int lhi = lane >> 4;

    // staging descriptors: offv = ch*HW + iy*64+ix (or -1), wadS encodes p,ch
    int offv[6], wadS[6];
#pragma unroll
    for (int it = 0; it < 6; ++it) {
        int e = tid + it * 256;
        int ch = (e * 3237) >> 20;       // e/324 for e<1296
        int p = e - ch * 324;
        int hy = (p * 57) >> 10;         // p/18 for p<324
        int hx = p - hy * 18;
        int iy = ty + hy - 1, ix = tx + hx - 1;
        bool in = ((unsigned)iy < 64u) & ((unsigned)ix < 64u);
        offv[it] = in ? (ch * HW + iy * 64 + ix) : -1;
        int key = (p >> 1) & 3;
        wadS[it] = p * 64 + ((ch ^ key) << 4);
    }

    const float* h1g = h1 + (size_t)(b * COUT + g * 32) * HW;

    float vreg[6];
    uint4 ereg[6];
    unsigned sreg[6];
    // prologue: load+expand chunk 0; load chunk 1
#pragma unroll
    for (int it = 0; it < 6; ++it)
        if (it < 5 || tid < 16)
            vreg[it] = (offv[it] >= 0) ? h1g[offv[it]] : 0.0f;
#pragma unroll
    for (int it = 0; it < 6; ++it)
        if (it < 5 || tid < 16)
            expand_elem(vreg[it], offv[it] >= 0, ereg[it], sreg[it]);
#pragma unroll
    for (int it = 0; it < 6; ++it)
        if (it < 5 || tid < 16)
            vreg[it] = (offv[it] >= 0) ? h1g[4 * HW + offv[it]] : 0.0f;

    f32x4 acc[4][2];
#pragma unroll
    for (int y = 0; y < 4; ++y)
#pragma unroll
        for (int nf = 0; nf < 2; ++nf) {
            float bias = bb2[g * 32 + nf * 16 + lrow];
            acc[y][nf] = (f32x4){bias, bias, bias, bias};
        }

    const int pbase0 = (w * 4) * 18 + lrow;

    for (int cc = 0; cc < 8; ++cc) {
        // dx=0 B-frags in flight across the stage section
        const bf16x8* wpc = wfs + (size_t)((g * 8 + cc) * 18) * 64;
        bf16x8 bfA[3][2];
#pragma unroll
        for (int dy = 0; dy < 3; ++dy)
#pragma unroll
            for (int nf = 0; nf < 2; ++nf)
                bfA[dy][nf] = wpc[(dy * 2 + nf) * 64 + lane];

        __syncthreads();                 // spl free (prev MFMA done)
        // short stage section: pure ds_writes from pre-expanded regs
#pragma unroll
        for (int it = 0; it < 6; ++it)
            if (it < 5 || tid < 16)
                stage_write(spl, slu, ereg[it], sreg[it], wadS[it], cc);
        __syncthreads();                 // staging complete

        bf16x8 bfB[3][2];
        // dx=0
#pragma unroll
        for (int dy = 0; dy < 3; ++dy)
#pragma unroll
            for (int nf = 0; nf < 2; ++nf)
                bfB[dy][nf] = wpc[(6 + dy * 2 + nf) * 64 + lane];
        __builtin_amdgcn_s_setprio(1);
        mfma_hr(spl, bfA, pbase0 + 0, lhi, acc);
        __builtin_amdgcn_s_setprio(0);
        // dx=1
#pragma unroll
        for (int dy = 0; dy < 3; ++dy)
#pragma unroll
            for (int nf = 0; nf < 2; ++nf) {
                bfA[dy][nf] = bfB[dy][nf];
                bfB[dy][nf] = wpc[(12 + dy * 2 + nf) * 64 + lane];
            }
        __builtin_amdgcn_s_setprio(1);
        mfma_hr(spl, bfA, pbase0 + 1, lhi, acc);
        __builtin_amdgcn_s_setprio(0);
        // expansion for cc+1 (VALU, overlaps MFMA pipe) + loads for cc+2
        if (cc < 7) {
#pragma unroll
            for (int it = 0; it < 6; ++it)
                if (it < 5 || tid < 16)
                    expand_elem(vreg[it], offv[it] >= 0, ereg[it], sreg[it]);
        }
        if (cc < 6) {
#pragma unroll
            for (int it = 0; it < 6; ++it)
                if (it < 5 || tid < 16)
                    vreg[it] = (offv[it] >= 0)
                        ? h1g[(size_t)((cc + 2) * 4) * HW + offv[it]] : 0.0f;
        }
        // dx=2
#pragma unroll
        for (int dy = 0; dy < 3; ++dy)
#pragma unroll
            for (int nf = 0; nf < 2; ++nf)
                bfA[dy][nf] = bfB[dy][nf];
        __builtin_amdgcn_s_setprio(1);
        mfma_hr(spl, bfA, pbase0 + 2, lhi, acc);
        __builtin_amdgcn_s_setprio(0);
    }

    // base branch: silu plane, K = 32 channels
#pragma unroll
    for (int dx = 0; dx < 3; ++dx) {
        bf16x8 bf[3][2];
        const bf16x8* wp = wfb + (size_t)(((g * 3 + dx) * 3) * 2) * 64;
#pragma unroll
        for (int dy = 0; dy < 3; ++dy)
#pragma unroll
            for (int nf = 0; nf < 2; ++nf)
                bf[dy][nf] = wp[(dy * 2 + nf) * 64 + lane];
        __builtin_amdgcn_s_setprio(1);
        mfma_hr(slu, bf, pbase0 + dx, lhi, acc);
        __builtin_amdgcn_s_setprio(0);
    }

    // write: D row (m) = x = lhi*4 + reg, col (n) = co = lrow
#pragma unroll
    for (int y = 0; y < 4; ++y) {
        int oy = ty + w * 4 + y;
#pragma unroll
        for (int nf = 0; nf < 2; ++nf) {
            int co = g * 32 + nf * 16 + lrow;
            float4 o = {acc[y][nf][0], acc[y][nf][1], acc[y][nf][2], acc[y][nf][3]};
            *reinterpret_cast<float4*>(
                &h2[(((size_t)b * COUT + co) * 64 + oy) * 64 + tx + lhi * 4]) = o;
        }
    }

    // fused BN partial sums (deterministic)
    float s0 = 0.0f, q0 = 0.0f, s1 = 0.0f, q1 = 0.0f;
#pragma unroll
    for (int y = 0; y < 4; ++y)
#pragma unroll
        for (int i = 0; i < 4; ++i) {
            float a0 = acc[y][0][i], a1 = acc[y][1][i];
            s0 += a0; q0 = fmaf(a0, a0, q0);
            s1 += a1; q1 = fmaf(a1, a1, q1);
        }
    s0 += __shfl_xor(s0, 16); s0 += __shfl_xor(s0, 32);
    q0 += __shfl_xor(q0, 16); q0 += __shfl_xor(q0, 32);
    s1 += __shfl_xor(s1, 16); s1 += __shfl_xor(s1, 32);
    q1 += __shfl_xor(q1, 16); q1 += __shfl_xor(q1, 32);
    __syncthreads();
    float* stb = reinterpret_cast<float*>(lds);
    if (lane < 16) {
        int base = (w * 16 + lane) * 4;
        stb[base] = s0; stb[base + 1] = q0;
        stb[base + 2] = s1; stb[base + 3] = q1;
    }
    __syncthreads();
    if (tid < 64) {
        int slot = tid >> 1;
        int j = tid & 1;
        int lr = slot & 15, nf = slot >> 4;
        float a = 0.0f;
#pragma unroll
        for (int wv = 0; wv < 4; ++wv)
            a += stb[(wv * 16 + lr) * 4 + nf * 2 + j];
        partial2[blk * 64 + tid] = a;
    }
}

// ---- BN stats: one block per channel, reduce 256 block-partials ----
__global__ void __launch_bounds__(256) bnstat2_kernel(
    const float* __restrict__ partial2, const float* __restrict__ gamma,
    const float* __restrict__ beta, float* __restrict__ stats) {
    int co = blockIdx.x;
    int t = threadIdx.x;
    int g = co >> 5, loc = co & 31;
    int b = t >> 4, tile = t & 15;
    int blk = (b * 8 + g) * 16 + tile;
    float s = partial2[blk * 64 + loc * 2];
    float ss = partial2[blk * 64 + loc * 2 + 1];
    __shared__ float r1[256], r2[256];
    r1[t] = s; r2[t] = ss;
    __syncthreads();
    for (int o = 128; o > 0; o >>= 1) {
        if (t < o) { r1[t] += r1[t + o]; r2[t] += r2[t + o]; }
        __syncthreads();
    }
    if (t == 0) {
        const float invn = 1.0f / 65536.0f;
        float mean = r1[0] * invn;
        float var = r2[0] * invn - mean * mean;
        float sc = gamma[co] * rsqrtf(var + 1e-5f);
        stats[2 * co] = sc;
        stats[2 * co + 1] = beta[co] - mean * sc;
    }
}

// ---- BN apply (in place on d_out) ----
__global__ void __launch_bounds__(256) bnapply_kernel(
    float* __restrict__ h2, const float* __restrict__ stats, int n4) {
    int i = blockIdx.x * 256 + threadIdx.x;
    if (i >= n4) return;
    int co = (i >> 10) & 255;
    float sc = stats[2 * co], sh = stats[2 * co + 1];
    float4 v = reinterpret_cast<float4*>(h2)[i];
    float4 o;
    o.x = fmaf(v.x, sc, sh);
    o.y = fmaf(v.y, sc, sh);
    o.z = fmaf(v.z, sc, sh);
    o.w = fmaf(v.w, sc, sh);
    reinterpret_cast<float4*>(h2)[i] = o;
}

extern "C" void kernel_launch(void* const* d_in, const int* in_sizes, int n_in,
                              void* d_out, int out_size, void* d_ws, size_t ws_size,
                              hipStream_t stream) {
    const float* x   = (const float*)d_in[0];
    const float* wb1 = (const float*)d_in[1];
    const float* bb1 = (const float*)d_in[2];
    const float* ws1 = (const float*)d_in[3];
    const float* wb2 = (const float*)d_in[4];
    const float* bb2 = (const float*)d_in[5];
    const float* ws2 = (const float*)d_in[6];
    const float* gamma = (const float*)d_in[7];
    const float* beta  = (const float*)d_in[8];

    char* ws = (char*)d_ws;
    unsigned short* wfs  = (unsigned short*)ws;              // 1,179,648 B
    unsigned short* wfb  = (unsigned short*)(ws + 1179648);  // 147,456 B
    unsigned short* wf1s = (unsigned short*)(ws + 1327104);  // 65,536 B
    unsigned short* wf1b = (unsigned short*)(ws + 1392640);  // 16,384 B
    float* partial2 = (float*)(ws + 1409024);                // 524,288 B
    float* stats    = (float*)(ws + 1933312);                // 2,048 B
    float* h1       = (float*)(ws + 1935360);                // 67,108,864 B

    float* h2 = (float*)d_out;   // conv2 output in d_out; BN in-place

    repack2_kernel<<<(WFS_ELEMS + 255) / 256, 256, 0, stream>>>(
        wb1, ws1, wb2, ws2, wfs, wfb, wf1s, wf1b);
    kan1m_kernel<<<BATCH * GROUPS * 16, 256, 0, stream>>>(
        x, (const bf16x8*)wf1s, (const bf16x8*)wf1b, bb1, h1);
    kan2_mfma4_kernel<<<BATCH * GROUPS * 16, 256, 0, stream>>>(
        h1, (const bf16x8*)wfs, (const bf16x8*)wfb, bb2, h2, partial2);
    bnstat2_kernel<<<COUT, 256, 0, stream>>>(partial2, gamma, beta, stats);
    bnapply_kernel<<<(4194304 + 255) / 256, 256, 0, stream>>>(
        h2, stats, 4194304);
}

// Round 12
// 150.609 us; speedup vs baseline: 3.9723x; 1.0395x over previous
//
#include <hip/hip_runtime.h>
#include <hip/hip_bf16.h>
#include <stdint.h>

// GSC_kan: two grouped KAN convs (1x1, 3x3; G=8) + BatchNorm.
// Round 12: R11 neutral -> the VALU bloat is per-cc addressing overhead,
// not expansion placement. Hoist all loop-invariant LDS addresses (raA),
// walk one B-frag pointer, named one-ahead frag buffers (no copies),
// incremental slu addressing, silu via exp2+rcp builtins.

#define NB 8
#define NF 9
#define CIN 128
#define COUT 256
#define GROUPS 8
#define HW 4096
#define BATCH 16

#define WFS_ELEMS 589824   // 256 * 32 * 8 * 9
#define WFB_ELEMS 73728    // 256 * 32 * 9
#define WF1S_ELEMS 32768   // 8g * 4cc * 2nf * 64 * 8
#define WF1B_ELEMS 8192    // 8g * 2nf * 64 * 8

typedef __attribute__((ext_vector_type(8))) short bf16x8;
typedef __attribute__((ext_vector_type(4))) float f32x4;

__device__ __forceinline__ unsigned bf16r(float f) {
    union { float f; unsigned u; } c; c.f = f;
    unsigned r = c.u + 0x7FFF + ((c.u >> 16) & 1);   // RNE
    return r >> 16;
}

__device__ __forceinline__ float silu_fast(float v) {
    float e = __builtin_amdgcn_exp2f(v * -1.44269504088896f);  // e^-v
    return v * __builtin_amdgcn_rcpf(1.0f + e);
}

// uniform-knot cubic B-spline: 4 nonzero cardinal weights at interval k.
__device__ __forceinline__ void spline_w(float v, float& w0, float& w1,
                                         float& w2, float& w3, int& k) {
    float s = (v + 2.2f) * 2.5f;
    float fk = floorf(s);
    k = (int)fk;
    float u = s - fk;
    float um = 1.0f - u;
    float u2 = u * u, u3 = u2 * u;
    w0 = um * um * um * (1.0f / 6.0f);
    w1 = (3.0f * u3 - 6.0f * u2 + 4.0f) * (1.0f / 6.0f);
    w2 = (-3.0f * u3 + 3.0f * u2 + 3.0f * u + 1.0f) * (1.0f / 6.0f);
    w3 = u3 * (1.0f / 6.0f);
}

// ---- build the 8-bf16 spline row (zeros except w0..w3 at kk..kk+3) ----
__device__ __forceinline__ uint4 spline_row(float v, bool in, float& sv) {
    sv = silu_fast(v);
    float w0, w1, w2, w3; int k;
    spline_w(v, w0, w1, w2, w3, k);
    unsigned W0, W1;
    asm("v_cvt_pk_bf16_f32 %0, %1, %2" : "=v"(W0) : "v"(w0), "v"(w1));
    asm("v_cvt_pk_bf16_f32 %0, %1, %2" : "=v"(W1) : "v"(w2), "v"(w3));
    int kk = in ? (k - 3) : 99;                  // sentinel -> all-zero row
    unsigned odd = (unsigned)kk & 1u;
    unsigned A = W0 << 16;
    unsigned B = (W0 >> 16) | (W1 << 16);
    unsigned C = W1 >> 16;
    unsigned t0 = odd ? A : W0;
    unsigned t1 = odd ? B : W1;
    unsigned t2 = odd ? C : 0u;
    int q = kk >> 1;                             // floor((k-3)/2)
    uint4 pk;
    pk.x = (q == 0) ? t0 : (q == -1) ? t1 : (q == -2) ? t2 : 0u;
    pk.y = (q == 1) ? t0 : (q == 0)  ? t1 : (q == -1) ? t2 : 0u;
    pk.z = (q == 2) ? t0 : (q == 1)  ? t1 : (q == 0)  ? t2 : 0u;
    pk.w = (q == 3) ? t0 : (q == 2)  ? t1 : (q == 1)  ? t2 : 0u;
    return pk;
}

__device__ __forceinline__ void expand_elem(float v, bool in,
                                            uint4& pk, unsigned& su) {
    float sv;
    pk = spline_row(v, in, sv);
    su = bf16r(sv);
}

// ---- repack: wfs/wfb (kan2) and wf1s/wf1b (kan1) bf16 B-fragment layouts ----
__global__ void __launch_bounds__(256) repack2_kernel(
    const float* __restrict__ wb1, const float* __restrict__ ws1,
    const float* __restrict__ wb2, const float* __restrict__ ws2,
    unsigned short* __restrict__ wfs, unsigned short* __restrict__ wfb,
    unsigned short* __restrict__ wf1s, unsigned short* __restrict__ wf1b) {
    int i = blockIdx.x * 256 + threadIdx.x;
    if (i < WF1S_ELEMS) {   // [g][cc4][nf2][lane64][j8]
        int j = i & 7;
        int lane = (i >> 3) & 63;
        int nf = (i >> 9) & 1;
        int cc = (i >> 10) & 3;
        int g = i >> 12;
        int c_loc = cc * 4 + (lane >> 4);
        int cog = g * 32 + nf * 16 + (lane & 15);
        wf1s[i] = (unsigned short)bf16r(ws1[cog * 128 + c_loc * 8 + j]);
    }
    if (i < WF1B_ELEMS) {   // [g][nf2][lane64][j8], k=(lane>>4)*8+j, zero k>=16
        int j = i & 7;
        int lane = (i >> 3) & 63;
        int nf = (i >> 9) & 1;
        int g = (i >> 10) & 7;
        int k = (lane >> 4) * 8 + j;
        int cog = g * 32 + nf * 16 + (lane & 15);
        wf1b[i] = (k < 16) ? (unsigned short)bf16r(wb1[cog * 16 + k]) : 0;
    }
    if (i < WFB_ELEMS) {    // [g][dx3][dy3][nf2][lane64][j8]
        int j = i & 7;
        int lane = (i >> 3) & 63;
        int nf = (i >> 9) & 1;
        int t = i >> 10;
        int dy = t % 3; t /= 3;
        int dx = t % 3; t /= 3;
        int g = t;
        int ch = (lane >> 4) * 8 + j;
        int cog = g * 32 + nf * 16 + (lane & 15);
        wfb[i] = (unsigned short)bf16r(wb2[((cog * 32 + ch) * 3 + dy) * 3 + dx]);
    }
    if (i < WFS_ELEMS) {    // [g][cc8][dx3][dy3][nf2][lane64][j8]
        int j = i & 7;
        int t = i >> 3;
        int lane = t & 63; t >>= 6;
        int nf = t & 1; t >>= 1;
        int dy = t % 3; t /= 3;
        int dx = t % 3; t /= 3;
        int cc = t & 7; t >>= 3;
        int g = t;
        int c_loc = cc * 4 + (lane >> 4);
        int cog = g * 32 + nf * 16 + (lane & 15);
        float v = ws2[((cog * 256 + c_loc * 8 + j) * 3 + dy) * 3 + dx];
        wfs[i] = (unsigned short)bf16r(v);
    }
}

// ---- layer 1: 1x1 grouped KAN conv via bf16 MFMA ----
__global__ void __launch_bounds__(256, 4) kan1m_kernel(
    const float* __restrict__ x, const bf16x8* __restrict__ wf1s,
    const bf16x8* __restrict__ wf1b, const float* __restrict__ bb1,
    float* __restrict__ h1) {
    __shared__ __align__(16) unsigned char lds[32768];
    unsigned char* spl = lds;            // 16384: [pos256][64B] swizzled
    unsigned char* slu = lds + 16384;    // 16384: [pos256][64B] K=32 (16ch+16z)

    const int tid = threadIdx.x;
    const int lane = tid & 63;
    const int w = tid >> 6;
    const int blk = blockIdx.x;          // (b*8+g)*16 + tile
    const int tile = blk & 15;
    const int g = (blk >> 4) & 7;
    const int b = blk >> 7;
    const int lrow = lane & 15;
    const int lhi = lane >> 4;
    const int posg0 = tile * 256;

    {
        int key = (tid >> 1) & 3;
        uint4 z = {0, 0, 0, 0};
        *reinterpret_cast<uint4*>(slu + tid * 64 + ((2 ^ key) << 4)) = z;
        *reinterpret_cast<uint4*>(slu + tid * 64 + ((3 ^ key) << 4)) = z;
    }

    const float* xg = x + ((size_t)b * CIN + g * 16) * HW + posg0;

    float xreg[4];
#pragma unroll
    for (int it = 0; it < 4; ++it) xreg[it] = xg[it * HW + tid];

    f32x4 acc[4][2];
#pragma unroll
    for (int m = 0; m < 4; ++m)
#pragma unroll
        for (int nf = 0; nf < 2; ++nf) {
            float bias = bb1[g * 32 + nf * 16 + lrow];
            acc[m][nf] = (f32x4){bias, bias, bias, bias};
        }

    for (int cc = 0; cc < 4; ++cc) {
        __syncthreads();
        int key = (tid >> 1) & 3;
#pragma unroll
        for (int it = 0; it < 4; ++it) {
            float sv;
            uint4 pk = spline_row(xreg[it], true, sv);
            *reinterpret_cast<uint4*>(spl + tid * 64 + ((it ^ key) << 4)) = pk;
            int cg = cc * 4 + it;
            *reinterpret_cast<unsigned short*>(
                slu + tid * 64 + (((cg >> 3) ^ key) << 4) + (cg & 7) * 2) =
                (unsigned short)bf16r(sv);
        }
        if (cc < 3) {
#pragma unroll
            for (int it = 0; it < 4; ++it)
                xreg[it] = xg[((cc + 1) * 4 + it) * HW + tid];
        }
        __syncthreads();
        const bf16x8* wpc = wf1s + (size_t)((g * 4 + cc) * 2) * 64;
        bf16x8 bf0 = wpc[lane];
        bf16x8 bf1 = wpc[64 + lane];
#pragma unroll
        for (int m = 0; m < 4; ++m) {
            int pos = w * 64 + m * 16 + lrow;
            int ra = pos * 64 + ((lhi ^ ((pos >> 1) & 3)) << 4);
            bf16x8 af = *reinterpret_cast<const bf16x8*>(spl + ra);
            acc[m][0] = __builtin_amdgcn_mfma_f32_16x16x32_bf16(af, bf0, acc[m][0], 0, 0, 0);
            acc[m][1] = __builtin_amdgcn_mfma_f32_16x16x32_bf16(af, bf1, acc[m][1], 0, 0, 0);
        }
    }
    {
        const bf16x8* wpb = wf1b + (size_t)(g * 2) * 64;
        bf16x8 bf0 = wpb[lane];
        bf16x8 bf1 = wpb[64 + lane];
#pragma unroll
        for (int m = 0; m < 4; ++m) {
            int pos = w * 64 + m * 16 + lrow;
            int ra = pos * 64 + ((lhi ^ ((pos >> 1) & 3)) << 4);
            bf16x8 af = *reinterpret_cast<const bf16x8*>(slu + ra);
            acc[m][0] = __builtin_amdgcn_mfma_f32_16x16x32_bf16(af, bf0, acc[m][0], 0, 0, 0);
            acc[m][1] = __builtin_amdgcn_mfma_f32_16x16x32_bf16(af, bf1, acc[m][1], 0, 0, 0);
        }
    }
#pragma unroll
    for (int m = 0; m < 4; ++m)
#pragma unroll
        for (int nf = 0; nf < 2; ++nf) {
            int co = g * 32 + nf * 16 + lrow;
            float4 o = {acc[m][nf][0], acc[m][nf][1], acc[m][nf][2], acc[m][nf][3]};
            *reinterpret_cast<float4*>(
                &h1[((size_t)b * COUT + co) * HW + posg0 + w * 64 + m * 16 + lhi * 4]) = o;
        }
}

// ---- MFMA over one dx tap-column with precomputed LDS addrs ----
__device__ __forceinline__ void mfma_hr(
    const unsigned char* __restrict__ base, const int (&ra)[6],
    const bf16x8 (&bf)[3][2], f32x4 (&acc)[4][2]) {
#pragma unroll
    for (int hr = 0; hr < 6; ++hr) {
        bf16x8 af = *reinterpret_cast<const bf16x8*>(base + ra[hr]);
#pragma unroll
        for (int dy = 0; dy < 3; ++dy) {
            int y = hr - dy;
            if (y >= 0 && y < 4) {
                acc[y][0] = __builtin_amdgcn_mfma_f32_16x16x32_bf16(af, bf[dy][0], acc[y][0], 0, 0, 0);
                acc[y][1] = __builtin_amdgcn_mfma_f32_16x16x32_bf16(af, bf[dy][1], acc[y][1], 0, 0, 0);
            }
        }
    }
}

// ---- layer 2: 3x3 grouped KAN conv, hoisted addressing ----
__global__ void __launch_bounds__(256, 3) kan2_mfma5_kernel(
    const float* __restrict__ h1, const bf16x8* __restrict__ wfs,
    const bf16x8* __restrict__ wfb, const float* __restrict__ bb2,
    float* __restrict__ h2, float* __restrict__ partial2) {
    __shared__ __align__(16) unsigned char lds[41472];
    unsigned char* spl = lds;            // 20736 B
    unsigned char* slu = lds + 20736;    // 20736 B

    const int tid = threadIdx.x;
    const int lane = tid & 63;
    const int w = tid >> 6;
    const int blk = blockIdx.x;
    const int tile = blk & 15;
    const int g = (blk >> 4) & 7;
    const int b = blk >> 7;
    const int ty = (tile >> 2) * 16, tx = (tile & 3) * 16;
    const int lrow = lane & 15;
    const int lhi = lane >> 4;

    // staging descriptors (all cc-invariant)
    int offv[6], wadS[6], sluB[6], keysh[6];
#pragma unroll
    for (int it = 0; it < 6; ++it) {
        int e = tid + it * 256;
        int ch = (e * 3237) >> 20;       // e/324 for e<1296
        int p = e - ch * 324;
        int hy = (p * 57) >> 10;         // p/18 for p<324
        int hx = p - hy * 18;
        int iy = ty + hy - 1, ix = tx + hx - 1;
        bool in = ((unsigned)iy < 64u) & ((unsigned)ix < 64u);
        offv[it] = in ? (ch * HW + iy * 64 + ix) : -1;
        int key = (p >> 1) & 3;
        wadS[it] = p * 64 + ((ch ^ key) << 4);
        sluB[it] = p * 64 + ch * 2;
        keysh[it] = key << 4;
    }

    // A-frag LDS read addrs (cc-invariant; also valid for slu base phase)
    const int pbase0 = (w * 4) * 18 + lrow;
    int raA[3][6];
#pragma unroll
    for (int dx = 0; dx < 3; ++dx)
#pragma unroll
        for (int hr = 0; hr < 6; ++hr) {
            int p = pbase0 + dx + hr * 18;
            raA[dx][hr] = p * 64 + ((lhi ^ ((p >> 1) & 3)) << 4);
        }

    const float* h1g = h1 + (size_t)(b * COUT + g * 32) * HW;

    float vreg[6];
    uint4 ereg[6];
    unsigned sreg[6];
    // prologue: load+expand chunk 0; load chunk 1
#pragma unroll
    for (int it = 0; it < 6; ++it)
        if (it < 5 || tid < 16)
            vreg[it] = (offv[it] >= 0) ? h1g[offv[it]] : 0.0f;
#pragma unroll
    for (int it = 0; it < 6; ++it)
        if (it < 5 || tid < 16)
            expand_elem(vreg[it], offv[it] >= 0, ereg[it], sreg[it]);
#pragma unroll
    for (int it = 0; it < 6; ++it)
        if (it < 5 || tid < 16)
            vreg[it] = (offv[it] >= 0) ? h1g[4 * HW + offv[it]] : 0.0f;

    f32x4 acc[4][2];
#pragma unroll
    for (int y = 0; y < 4; ++y)
#pragma unroll
        for (int nf = 0; nf < 2; ++nf) {
            float bias = bb2[g * 32 + nf * 16 + lrow];
            acc[y][nf] = (f32x4){bias, bias, bias, bias};
        }

    const bf16x8* wl = wfs + (size_t)(g * 8) * 18 * 64 + lane;

    for (int cc = 0; cc < 8; ++cc) {
        // dx=0 B-frags issued before stage (in flight across barrier)
        bf16x8 bf0[3][2];
#pragma unroll
        for (int dy = 0; dy < 3; ++dy)
#pragma unroll
            for (int nf = 0; nf < 2; ++nf)
                bf0[dy][nf] = wl[(dy * 2 + nf) * 64];

        __syncthreads();                 // spl free (prev MFMA done)
        {
            int t4 = (cc >> 1) << 4;
            int u8 = (cc & 1) << 3;
#pragma unroll
            for (int it = 0; it < 6; ++it)
                if (it < 5 || tid < 16) {
                    *reinterpret_cast<uint4*>(spl + wadS[it]) = ereg[it];
                    *reinterpret_cast<unsigned short*>(
                        slu + sluB[it] + (t4 ^ keysh[it]) + u8) =
                        (unsigned short)sreg[it];
                }
        }
        __syncthreads();                 // staging complete

        bf16x8 bf1[3][2], bf2[3][2];
#pragma unroll
        for (int dy = 0; dy < 3; ++dy)
#pragma unroll
            for (int nf = 0; nf < 2; ++nf)
                bf1[dy][nf] = wl[(6 + dy * 2 + nf) * 64];
        __builtin_amdgcn_s_setprio(1);
        mfma_hr(spl, raA[0], bf0, acc);
        __builtin_amdgcn_s_setprio(0);
#pragma unroll
        for (int dy = 0; dy < 3; ++dy)
#pragma unroll
            for (int nf = 0; nf < 2; ++nf)
                bf2[dy][nf] = wl[(12 + dy * 2 + nf) * 64];
        __builtin_amdgcn_s_setprio(1);
        mfma_hr(spl, raA[1], bf1, acc);
        __builtin_amdgcn_s_setprio(0);
        // expansion for cc+1 + loads for cc+2 (overlap MFMA pipe)
        if (cc < 7) {
#pragma unroll
            for (int it = 0; it < 6; ++it)
                if (it < 5 || tid < 16)
                    expand_elem(vreg[it], offv[it] >= 0, ereg[it], sreg[it]);
        }
        if (cc < 6) {
#pragma unroll
            for (int it = 0; it < 6; ++it)
                if (it < 5 || tid < 16)
                    vreg[it] = (offv[it] >= 0)
                        ? h1g[(size_t)((cc + 2) * 4) * HW + offv[it]] : 0.0f;
        }
        __builtin_amdgcn_s_setprio(1);
        mfma_hr(spl, raA[2], bf2, acc);
        __builtin_amdgcn_s_setprio(0);
        wl += 18 * 64;
    }

    // base branch: silu plane, K = 32 channels (reuses raA on slu)
    {
        const bf16x8* wlb = wfb + (size_t)(g * 3) * 6 * 64 + lane;
#pragma unroll
        for (int dx = 0; dx < 3; ++dx) {
            bf16x8 bf[3][2];
#pragma unroll
            for (int dy = 0; dy < 3; ++dy)
#pragma unroll
                for (int nf = 0; nf < 2; ++nf)
                    bf[dy][nf] = wlb[(dx * 6 + dy * 2 + nf) * 64];
            __builtin_amdgcn_s_setprio(1);
            mfma_hr(slu, raA[dx], bf, acc);
            __builtin_amdgcn_s_setprio(0);
        }
    }

    // write: D row (m) = x = lhi*4 + reg, col (n) = co = lrow
#pragma unroll
    for (int y = 0; y < 4; ++y) {
        int oy = ty + w * 4 + y;
#pragma unroll
        for (int nf = 0; nf < 2; ++nf) {
            int co = g * 32 + nf * 16 + lrow;
            float4 o = {acc[y][nf][0], acc[y][nf][1], acc[y][nf][2], acc[y][nf][3]};
            *reinterpret_cast<float4*>(
                &h2[(((size_t)b * COUT + co) * 64 + oy) * 64 + tx + lhi * 4]) = o;
        }
    }

    // fused BN partial sums (deterministic)
    float s0 = 0.0f, q0 = 0.0f, s1 = 0.0f, q1 = 0.0f;
#pragma unroll
    for (int y = 0; y < 4; ++y)
#pragma unroll
        for (int i = 0; i < 4; ++i) {
            float a0 = acc[y][0][i], a1 = acc[y][1][i];
            s0 += a0; q0 = fmaf(a0, a0, q0);
            s1 += a1; q1 = fmaf(a1, a1, q1);
        }
    s0 += __shfl_xor(s0, 16); s0 += __shfl_xor(s0, 32);
    q0 += __shfl_xor(q0, 16); q0 += __shfl_xor(q0, 32);
    s1 += __shfl_xor(s1, 16); s1 += __shfl_xor(s1, 32);
    q1 += __shfl_xor(q1, 16); q1 += __shfl_xor(q1, 32);
    __syncthreads();
    float* stb = reinterpret_cast<float*>(lds);
    if (lane < 16) {
        int base = (w * 16 + lane) * 4;
        stb[base] = s0; stb[base + 1] = q0;
        stb[base + 2] = s1; stb[base + 3] = q1;
    }
    __syncthreads();
    if (tid < 64) {
        int slot = tid >> 1;
        int j = tid & 1;
        int lr = slot & 15, nf = slot >> 4;
        float a = 0.0f;
#pragma unroll
        for (int wv = 0; wv < 4; ++wv)
            a += stb[(wv * 16 + lr) * 4 + nf * 2 + j];
        partial2[blk * 64 + tid] = a;
    }
}

// ---- BN stats: one block per channel, reduce 256 block-partials ----
__global__ void __launch_bounds__(256) bnstat2_kernel(
    const float* __restrict__ partial2, const float* __restrict__ gamma,
    const float* __restrict__ beta, float* __restrict__ stats) {
    int co = blockIdx.x;
    int t = threadIdx.x;
    int g = co >> 5, loc = co & 31;
    int b = t >> 4, tile = t & 15;
    int blk = (b * 8 + g) * 16 + tile;
    float s = partial2[blk * 64 + loc * 2];
    float ss = partial2[blk * 64 + loc * 2 + 1];
    __shared__ float r1[256], r2[256];
    r1[t] = s; r2[t] = ss;
    __syncthreads();
    for (int o = 128; o > 0; o >>= 1) {
        if (t < o) { r1[t] += r1[t + o]; r2[t] += r2[t + o]; }
        __syncthreads();
    }
    if (t == 0) {
        const float invn = 1.0f / 65536.0f;
        float mean = r1[0] * invn;
        float var = r2[0] * invn - mean * mean;
        float sc = gamma[co] * rsqrtf(var + 1e-5f);
        stats[2 * co] = sc;
        stats[2 * co + 1] = beta[co] - mean * sc;
    }
}

// ---- BN apply (in place on d_out) ----
__global__ void __launch_bounds__(256) bnapply_kernel(
    float* __restrict__ h2, const float* __restrict__ stats, int n4) {
    int i = blockIdx.x * 256 + threadIdx.x;
    if (i >= n4) return;
    int co = (i >> 10) & 255;
    float sc = stats[2 * co], sh = stats[2 * co + 1];
    float4 v = reinterpret_cast<float4*>(h2)[i];
    float4 o;
    o.x = fmaf(v.x, sc, sh);
    o.y = fmaf(v.y, sc, sh);
    o.z = fmaf(v.z, sc, sh);
    o.w = fmaf(v.w, sc, sh);
    reinterpret_cast<float4*>(h2)[i] = o;
}

extern "C" void kernel_launch(void* const* d_in, const int* in_sizes, int n_in,
                              void* d_out, int out_size, void* d_ws, size_t ws_size,
                              hipStream_t stream) {
    const float* x   = (const float*)d_in[0];
    const float* wb1 = (const float*)d_in[1];
    const float* bb1 = (const float*)d_in[2];
    const float* ws1 = (const float*)d_in[3];
    const float* wb2 = (const float*)d_in[4];
    const float* bb2 = (const float*)d_in[5];
    const float* ws2 = (const float*)d_in[6];
    const float* gamma = (const float*)d_in[7];
    const float* beta  = (const float*)d_in[8];

    char* ws = (char*)d_ws;
    unsigned short* wfs  = (unsigned short*)ws;              // 1,179,648 B
    unsigned short* wfb  = (unsigned short*)(ws + 1179648);  // 147,456 B
    unsigned short* wf1s = (unsigned short*)(ws + 1327104);  // 65,536 B
    unsigned short* wf1b = (unsigned short*)(ws + 1392640);  // 16,384 B
    float* partial2 = (float*)(ws + 1409024);                // 524,288 B
    float* stats    = (float*)(ws + 1933312);                // 2,048 B
    float* h1       = (float*)(ws + 1935360);                // 67,108,864 B

    float* h2 = (float*)d_out;   // conv2 output in d_out; BN in-place

    repack2_kernel<<<(WFS_ELEMS + 255) / 256, 256, 0, stream>>>(
        wb1, ws1, wb2, ws2, wfs, wfb, wf1s, wf1b);
    kan1m_kernel<<<BATCH * GROUPS * 16, 256, 0, stream>>>(
        x, (const bf16x8*)wf1s, (const bf16x8*)wf1b, bb1, h1);
    kan2_mfma5_kernel<<<BATCH * GROUPS * 16, 256, 0, stream>>>(
        h1, (const bf16x8*)wfs, (const bf16x8*)wfb, bb2, h2, partial2);
    bnstat2_kernel<<<COUT, 256, 0, stream>>>(partial2, gamma, beta, stats);
    bnapply_kernel<<<(4194304 + 255) / 256, 256, 0, stream>>>(
        h2, stats, 4194304);
}